// Round 2
// baseline (1664.375 us; speedup 1.0000x reference)
//
#include <hip/hip_runtime.h>
#include <hip/hip_bf16.h>
#include <stdint.h>
#include <stddef.h>

typedef __hip_bfloat16 bf16;
typedef __attribute__((ext_vector_type(8))) short short8;
typedef __attribute__((ext_vector_type(4))) float f32x4;

__device__ __forceinline__ float dsigm(float z){ return 1.f/(1.f+expf(-z)); }

// split fp32 -> hi (bit-truncated bf16) + lo (rounded bf16 residual); hi+lo ~ 16 mantissa bits
__device__ __forceinline__ void split1(float v, unsigned short& h, unsigned short& l) {
  unsigned int u = __builtin_bit_cast(unsigned int, v);
  h = (unsigned short)(u >> 16);
  float hf = __builtin_bit_cast(float, u & 0xFFFF0000u);
  bf16 lb = __float2bfloat16(v - hf);
  l = __builtin_bit_cast(unsigned short, lb);
}

//==================== 1. time-shift lerp -> fp32 operands ====================
__global__ void k_prep(const float* __restrict__ hs,
    const float* __restrict__ mr, const float* __restrict__ mw, const float* __restrict__ mk,
    const float* __restrict__ mv, const float* __restrict__ ma,
    float* __restrict__ oxr, float* __restrict__ oxw, float* __restrict__ oxk,
    float* __restrict__ oxv, float* __restrict__ oxa)
{
  size_t id = (size_t)blockIdx.x*256u + threadIdx.x;
  if (id >= (size_t)4194304) return;
  int c = (int)(id & 1023);
  int t = (int)((id >> 10) & 2047);
  float cur = hs[id];
  float prev = (t > 0) ? hs[id - 1024] : 0.f;
  float d = prev - cur;
  oxr[id] = fmaf(d, mr[c], cur);
  oxw[id] = fmaf(d, mw[c], cur);
  oxk[id] = fmaf(d, mk[c], cur);
  oxv[id] = fmaf(d, mv[c], cur);
  oxa[id] = fmaf(d, ma[c], cur);
}

//==================== 2. weight transpose (fp32) ====================
// dst[Cpad][R] = src[R][Cc]^T, rows Cc..Cpad zero-filled.
struct SrcP { const float* p[10]; };
struct DstP { float* p[10]; };

__global__ void k_transpose(SrcP S, DstP Dd)
{
  static constexpr int TR[10]  = {1024,1024,1024,1024,1024,  64,1024,  64,1024, 128};
  static constexpr int TCC[10] = {1024,1024,1024,1024,  64,1024,  64,1024, 128,1024};
  static constexpr int TCP[10] = {1024,1024,1024,1024, 128,1024, 128,1024, 128,1024};
  int z = blockIdx.z;
  int R = TR[z], Cc = TCC[z], Cp = TCP[z];
  int n0 = blockIdx.x * 32, r0 = blockIdx.y * 32;
  if (n0 >= Cp || r0 >= R) return;
  const float* src = S.p[z];
  float* dst = Dd.p[z];
  int tx = threadIdx.x, ty = threadIdx.y;
  __shared__ float tile[32][33];
  if (n0 < Cc) {
#pragma unroll
    for (int i = 0; i < 4; ++i)
      tile[ty + 8*i][tx] = src[(size_t)(r0 + ty + 8*i)*Cc + n0 + tx];
    __syncthreads();
#pragma unroll
    for (int i = 0; i < 4; ++i)
      dst[(size_t)(n0 + ty + 8*i)*R + r0 + tx] = tile[tx][ty + 8*i];
  } else {
#pragma unroll
    for (int i = 0; i < 4; ++i)
      dst[(size_t)(n0 + ty + 8*i)*R + r0 + tx] = 0.f;
  }
}

//==================== 3. split-bf16 MFMA GEMM (fp32-accurate) ====================
// C[M][N] = A[M][K] (fp32) * Bt[N][K]^T (fp32). tile 128x128, BK=32, 4 waves.
// mode: 0 none | 1 ew=e^-0.5*sigmoid(x+bias) | 2 sigmoid(x+bias) | 3 x+bias
__global__ __launch_bounds__(256) void k_gemm_split(
    const float* __restrict__ A, int lda,
    const float* __restrict__ Bt, int ldb,
    float* __restrict__ C, int ldc,
    const float* __restrict__ bias, int mode, int K)
{
  __shared__ __align__(16) unsigned short AsH[128*32];
  __shared__ __align__(16) unsigned short AsL[128*32];
  __shared__ __align__(16) unsigned short BsH[128*32];
  __shared__ __align__(16) unsigned short BsL[128*32];
  const int tid = threadIdx.x;
  const int l = tid & 63, w = tid >> 6;
  const int wm = w >> 1, wn = w & 1;
  const int rowBase = blockIdx.x * 128, colBase = blockIdx.y * 128;
  const int lrow = l & 15, kid = (l >> 4) * 8;

  f32x4 acc[4][4];
#pragma unroll
  for (int i = 0; i < 4; ++i)
#pragma unroll
    for (int j = 0; j < 4; ++j) { f32x4 z = {0.f,0.f,0.f,0.f}; acc[i][j] = z; }

  const int nk = K >> 5;
  for (int kt = 0; kt < nk; ++kt) {
#pragma unroll
    for (int rr = 0; rr < 4; ++rr) {
      int idx = rr*256 + tid;            // 0..1023 float4 slots (128 rows x 8)
      int ar = idx >> 3, ac = (idx & 7) * 4;
      float4 va = *(const float4*)(A  + (size_t)(rowBase + ar)*lda + kt*32 + ac);
      float4 vb = *(const float4*)(Bt + (size_t)(colBase + ar)*ldb + kt*32 + ac);
      ushort4 ha, la, hb, lb;
      split1(va.x, ha.x, la.x); split1(va.y, ha.y, la.y);
      split1(va.z, ha.z, la.z); split1(va.w, ha.w, la.w);
      split1(vb.x, hb.x, lb.x); split1(vb.y, hb.y, lb.y);
      split1(vb.z, hb.z, lb.z); split1(vb.w, hb.w, lb.w);
      *(ushort4*)&AsH[ar*32 + ac] = ha;
      *(ushort4*)&AsL[ar*32 + ac] = la;
      *(ushort4*)&BsH[ar*32 + ac] = hb;
      *(ushort4*)&BsL[ar*32 + ac] = lb;
    }
    __syncthreads();
    short8 fah[4], fal[4], fbh[4], fbl[4];
#pragma unroll
    for (int mt = 0; mt < 4; ++mt) {
      int ro = (wm*64 + mt*16 + lrow)*32 + kid;
      fah[mt] = *(const short8*)&AsH[ro];
      fal[mt] = *(const short8*)&AsL[ro];
    }
#pragma unroll
    for (int nt = 0; nt < 4; ++nt) {
      int ro = (wn*64 + nt*16 + lrow)*32 + kid;
      fbh[nt] = *(const short8*)&BsH[ro];
      fbl[nt] = *(const short8*)&BsL[ro];
    }
#pragma unroll
    for (int mt = 0; mt < 4; ++mt)
#pragma unroll
      for (int nt = 0; nt < 4; ++nt) {
        acc[mt][nt] = __builtin_amdgcn_mfma_f32_16x16x32_bf16(fah[mt], fbh[nt], acc[mt][nt], 0, 0, 0);
        acc[mt][nt] = __builtin_amdgcn_mfma_f32_16x16x32_bf16(fal[mt], fbh[nt], acc[mt][nt], 0, 0, 0);
        acc[mt][nt] = __builtin_amdgcn_mfma_f32_16x16x32_bf16(fah[mt], fbl[nt], acc[mt][nt], 0, 0, 0);
      }
    __syncthreads();
  }
#pragma unroll
  for (int mt = 0; mt < 4; ++mt) {
    int row = rowBase + wm*64 + mt*16 + (l >> 4)*4;
#pragma unroll
    for (int nt = 0; nt < 4; ++nt) {
      int col = colBase + wn*64 + nt*16 + (l & 15);
      float bv = (bias != nullptr) ? bias[col] : 0.f;
#pragma unroll
      for (int rg = 0; rg < 4; ++rg) {
        float v = acc[mt][nt][rg];
        if (mode == 1)      v = 0.60653066f * dsigm(v + bv);
        else if (mode == 2) v = dsigm(v + bv);
        else if (mode == 3) v = v + bv;
        C[(size_t)(row + rg)*ldc + col] = v;
      }
    }
  }
}

//==================== 4. activation between LoRA stages (fp32->fp32 compact) ====================
// in: fp32 [4096][128] (lda=128), out: fp32 [4096][1<<logc]. mode 0 id, 1 tanh, 2 sigmoid
__global__ void k_act(const float* __restrict__ in, float* __restrict__ out, int logc, int mode)
{
  int id = blockIdx.x * 256 + threadIdx.x;
  int r = id >> logc, c = id & ((1 << logc) - 1);
  float v = in[r * 128 + c];
  if (mode == 1) v = tanhf(v);
  else if (mode == 2) v = dsigm(v);
  out[id] = v;
}

//==================== 5. scan prep: kk normalize + k update ====================
__global__ void k_scanprep(float* __restrict__ kA, const float* __restrict__ aA,
                           const float* __restrict__ kkw, const float* __restrict__ kaw,
                           float* __restrict__ kkA)
{
  size_t gt = (size_t)blockIdx.x * 256u + threadIdx.x;
  int d = (int)(gt & 63);
  size_t flat = gt >> 6;
  int c = (int)((flat & 15) * 64 + d);
  float k0 = kA[gt], av = aA[gt];
  float kkv = k0 * kkw[c];
  float ss = kkv * kkv;
  ss += __shfl_xor(ss, 1);  ss += __shfl_xor(ss, 2);  ss += __shfl_xor(ss, 4);
  ss += __shfl_xor(ss, 8);  ss += __shfl_xor(ss, 16); ss += __shfl_xor(ss, 32);
  float inv = 1.f / fmaxf(sqrtf(ss), 1e-12f);
  kkA[gt] = kkv * inv;
  kA[gt]  = k0 * fmaf(av - 1.f, kaw[c], 1.f);
}

//==================== 6. sequential RWKV7 scan ====================
struct Step { float4 ew[2], kk[2], aa[2], kv[2], rr[2]; float vi; };

__device__ __forceinline__ void load_step(Step& d,
    const float* __restrict__ ewA, const float* __restrict__ kkA, const float* __restrict__ aA,
    const float* __restrict__ kA, const float* __restrict__ rA, const float* __restrict__ vA,
    size_t base, int j0, int i)
{
  const float4* pe = (const float4*)(ewA + base + j0);
  const float4* pq = (const float4*)(kkA + base + j0);
  const float4* pa = (const float4*)(aA  + base + j0);
  const float4* pk = (const float4*)(kA  + base + j0);
  const float4* pr = (const float4*)(rA  + base + j0);
  d.ew[0] = pe[0]; d.ew[1] = pe[1];
  d.kk[0] = pq[0]; d.kk[1] = pq[1];
  d.aa[0] = pa[0]; d.aa[1] = pa[1];
  d.kv[0] = pk[0]; d.kv[1] = pk[1];
  d.rr[0] = pr[0]; d.rr[1] = pr[1];
  d.vi = vA[base + i];
}

__device__ __forceinline__ void compute_step(Step& d, float* s,
    float* __restrict__ oA, size_t base, int i, int q)
{
  float sa = 0.f;
  sa += s[0]*d.kk[0].x; sa += s[1]*d.kk[0].y; sa += s[2]*d.kk[0].z; sa += s[3]*d.kk[0].w;
  sa += s[4]*d.kk[1].x; sa += s[5]*d.kk[1].y; sa += s[6]*d.kk[1].z; sa += s[7]*d.kk[1].w;
  sa += __shfl_xor(sa, 1); sa += __shfl_xor(sa, 2); sa += __shfl_xor(sa, 4);
  const float nsa = -sa, vi = d.vi;
  float op = 0.f;
#define SSTEP(SI, U, F) { float sc = s[SI]; \
    sc = sc*d.ew[U].F + nsa*(d.kk[U].F*d.aa[U].F) + vi*d.kv[U].F; \
    s[SI] = sc; op += sc*d.rr[U].F; }
  SSTEP(0,0,x) SSTEP(1,0,y) SSTEP(2,0,z) SSTEP(3,0,w)
  SSTEP(4,1,x) SSTEP(5,1,y) SSTEP(6,1,z) SSTEP(7,1,w)
#undef SSTEP
  op += __shfl_xor(op, 1); op += __shfl_xor(op, 2); op += __shfl_xor(op, 4);
  if (q == 0) oA[base + i] = op;
}

__global__ __launch_bounds__(512, 1) void k_scan(
    const float* __restrict__ rA, const float* __restrict__ ewA, const float* __restrict__ kA,
    const float* __restrict__ vA, const float* __restrict__ kkA, const float* __restrict__ aA,
    float* __restrict__ oA)
{
  const int bh = blockIdx.x;
  const int b = bh >> 4, h = bh & 15;
  const int tid = threadIdx.x;
  const int i = tid >> 3, q = tid & 7, j0 = q * 8;
  const size_t headOff = (size_t)b*2048*1024 + (size_t)h*64;
  float s[8];
#pragma unroll
  for (int c = 0; c < 8; ++c) s[c] = 0.f;
  Step d0, d1, d2, d3;
  load_step(d0, ewA,kkA,aA,kA,rA,vA, headOff,                    j0, i);
  load_step(d1, ewA,kkA,aA,kA,rA,vA, headOff + (size_t)1*1024,   j0, i);
  load_step(d2, ewA,kkA,aA,kA,rA,vA, headOff + (size_t)2*1024,   j0, i);
  for (int t = 0; t < 2048; t += 4) {
    load_step(d3, ewA,kkA,aA,kA,rA,vA, headOff + (size_t)(t+3)*1024, j0, i);
    compute_step(d0, s, oA, headOff + (size_t)t*1024, i, q);
    int t4 = (t+4 < 2048) ? t+4 : 2047;
    load_step(d0, ewA,kkA,aA,kA,rA,vA, headOff + (size_t)t4*1024, j0, i);
    compute_step(d1, s, oA, headOff + (size_t)(t+1)*1024, i, q);
    int t5 = (t+5 < 2048) ? t+5 : 2047;
    load_step(d1, ewA,kkA,aA,kA,rA,vA, headOff + (size_t)t5*1024, j0, i);
    compute_step(d2, s, oA, headOff + (size_t)(t+2)*1024, i, q);
    int t6 = (t+6 < 2048) ? t+6 : 2047;
    load_step(d2, ewA,kkA,aA,kA,rA,vA, headOff + (size_t)t6*1024, j0, i);
    compute_step(d3, s, oA, headOff + (size_t)(t+3)*1024, i, q);
  }
}

//==================== 7. GroupNorm + bonus + gate (fp32) ====================
__global__ void k_post(const float* __restrict__ oA, const float* __restrict__ rA,
    const float* __restrict__ kA, const float* __restrict__ vA,
    const float* __restrict__ rk, const float* __restrict__ gnw, const float* __restrict__ gnb,
    const float* __restrict__ gA, float* __restrict__ yA)
{
  size_t gt = (size_t)blockIdx.x * 256u + threadIdx.x;
  int d = (int)(gt & 63);
  size_t flat = gt >> 6;
  int c = (int)((flat & 15) * 64 + d);
  float ov = oA[gt];
  float ss = ov;
  ss += __shfl_xor(ss, 1);  ss += __shfl_xor(ss, 2);  ss += __shfl_xor(ss, 4);
  ss += __shfl_xor(ss, 8);  ss += __shfl_xor(ss, 16); ss += __shfl_xor(ss, 32);
  float mean = ss * (1.f/64.f);
  float dm = ov - mean;
  float vv = dm * dm;
  vv += __shfl_xor(vv, 1);  vv += __shfl_xor(vv, 2);  vv += __shfl_xor(vv, 4);
  vv += __shfl_xor(vv, 8);  vv += __shfl_xor(vv, 16); vv += __shfl_xor(vv, 32);
  float var = vv * (1.f/64.f);
  float y = dm * rsqrtf(var + 1e-5f) * gnw[c] + gnb[c];
  float pr = rA[gt] * kA[gt] * rk[c];
  pr += __shfl_xor(pr, 1);  pr += __shfl_xor(pr, 2);  pr += __shfl_xor(pr, 4);
  pr += __shfl_xor(pr, 8);  pr += __shfl_xor(pr, 16); pr += __shfl_xor(pr, 32);
  y += pr * vA[gt];
  y *= gA[gt];
  yA[gt] = y;
}

//==================== host ====================
extern "C" void kernel_launch(void* const* d_in, const int* in_sizes, int n_in,
                              void* d_out, int out_size, void* d_ws, size_t ws_size,
                              hipStream_t stream)
{
  (void)in_sizes; (void)n_in; (void)out_size; (void)ws_size;
  const float* hs     = (const float*)d_in[0];
  const float* x_r    = (const float*)d_in[1];
  const float* x_w    = (const float*)d_in[2];
  const float* x_k    = (const float*)d_in[3];
  const float* x_v    = (const float*)d_in[4];
  const float* x_a    = (const float*)d_in[5];
  const float* k_k    = (const float*)d_in[7];
  const float* k_a    = (const float*)d_in[8];
  const float* r_k    = (const float*)d_in[9];
  const float* W_r    = (const float*)d_in[10];
  const float* W_k    = (const float*)d_in[11];
  const float* W_v    = (const float*)d_in[12];
  const float* W_o    = (const float*)d_in[13];
  const float* wla    = (const float*)d_in[14];
  const float* wlb    = (const float*)d_in[15];
  const float* wlbias = (const float*)d_in[16];
  const float* ala    = (const float*)d_in[17];
  const float* alb    = (const float*)d_in[18];
  const float* albias = (const float*)d_in[19];
  const float* gla    = (const float*)d_in[20];
  const float* glb    = (const float*)d_in[21];
  const float* glbias = (const float*)d_in[22];
  const float* gnw    = (const float*)d_in[23];
  const float* gnb    = (const float*)d_in[24];

  char* ws = (char*)d_ws;
  constexpr size_t MB = 1024u*1024u;
  size_t cur = 0;
  auto take = [&](size_t bytes) { size_t o = cur; cur += (bytes + 255) & ~(size_t)255; return o; };

  // x operand buffers (fp32), later aliased once consumed
  float* xr_f = (float*)(ws + take(16*MB));
  float* xw_f = (float*)(ws + take(16*MB));
  float* xk_f = (float*)(ws + take(16*MB));
  float* xv_f = (float*)(ws + take(16*MB));
  float* xa_f = (float*)(ws + take(16*MB));
  float* Wr_t  = (float*)(ws + take(4*MB));
  float* Wk_t  = (float*)(ws + take(4*MB));
  float* Wv_t  = (float*)(ws + take(4*MB));
  float* Wo_t  = (float*)(ws + take(4*MB));
  float* wla_t = (float*)(ws + take(128*1024*4));   // [128][1024] padded
  float* wlb_t = (float*)(ws + take(1024*64*4));    // [1024][64]
  float* ala_t = (float*)(ws + take(128*1024*4));
  float* alb_t = (float*)(ws + take(1024*64*4));
  float* gla_t = (float*)(ws + take(128*1024*4));   // [128][1024]
  float* glb_t = (float*)(ws + take(1024*128*4));   // [1024][128]
  float* r_f  = (float*)(ws + take(16*MB));
  float* k_f  = (float*)(ws + take(16*MB));
  float* v_f  = (float*)(ws + take(16*MB));
  float* t1   = (float*)(ws + take(2*MB));          // [4096][128]
  float* t2   = (float*)(ws + take(2*MB));          // [4096][<=128] compact
  // aliases (lifetime-checked against launch order):
  float* ew_f = xr_f;   // xr consumed by r-GEMM before ew is written
  float* a_f  = xk_f;   // xk consumed by k-GEMM
  float* kk_f = xw_f;   // xw consumed by w-LoRA stage1
  float* g_f  = xv_f;   // xv consumed by v-GEMM
  float* y_f  = xa_f;   // xa consumed by a-LoRA stage1
  float* oF   = (float*)d_out;                      // scan output lives in d_out

  // 1. prep
  k_prep<<<16384, 256, 0, stream>>>(hs, x_r, x_w, x_k, x_v, x_a,
                                    xr_f, xw_f, xk_f, xv_f, xa_f);
  // 2. weight transposes
  SrcP sp; DstP dp;
  sp.p[0]=W_r; sp.p[1]=W_k; sp.p[2]=W_v; sp.p[3]=W_o;
  sp.p[4]=wla; sp.p[5]=wlb; sp.p[6]=ala; sp.p[7]=alb; sp.p[8]=gla; sp.p[9]=glb;
  dp.p[0]=Wr_t; dp.p[1]=Wk_t; dp.p[2]=Wv_t; dp.p[3]=Wo_t;
  dp.p[4]=wla_t; dp.p[5]=wlb_t; dp.p[6]=ala_t; dp.p[7]=alb_t; dp.p[8]=gla_t; dp.p[9]=glb_t;
  k_transpose<<<dim3(32,32,10), dim3(32,8), 0, stream>>>(sp, dp);

  // 3. big projections
  k_gemm_split<<<dim3(32,8), 256, 0, stream>>>(xr_f,1024, Wr_t,1024, r_f,1024, nullptr, 0, 1024);
  k_gemm_split<<<dim3(32,8), 256, 0, stream>>>(xk_f,1024, Wk_t,1024, k_f,1024, nullptr, 0, 1024);
  k_gemm_split<<<dim3(32,8), 256, 0, stream>>>(xv_f,1024, Wv_t,1024, v_f,1024, nullptr, 0, 1024);

  // 4. w-LoRA: tanh(xw@A) @ B + bias -> ew = e^-0.5*sigmoid(z)
  k_gemm_split<<<dim3(32,1), 256, 0, stream>>>(xw_f,1024, wla_t,1024, t1,128, nullptr, 0, 1024);
  k_act<<<1024, 256, 0, stream>>>(t1, t2, 6, 1);
  k_gemm_split<<<dim3(32,8), 256, 0, stream>>>(t2,64, wlb_t,64, ew_f,1024, wlbias, 1, 64);

  // 5. a-LoRA: sigmoid((xa@A)@B + bias)
  k_gemm_split<<<dim3(32,1), 256, 0, stream>>>(xa_f,1024, ala_t,1024, t1,128, nullptr, 0, 1024);
  k_act<<<1024, 256, 0, stream>>>(t1, t2, 6, 0);
  k_gemm_split<<<dim3(32,8), 256, 0, stream>>>(t2,64, alb_t,64, a_f,1024, albias, 2, 64);

  // 6. g-LoRA: sigmoid(r@A) @ B + bias
  k_gemm_split<<<dim3(32,1), 256, 0, stream>>>(r_f,1024, gla_t,1024, t1,128, nullptr, 0, 1024);
  k_act<<<2048, 256, 0, stream>>>(t1, t2, 7, 2);
  k_gemm_split<<<dim3(32,8), 256, 0, stream>>>(t2,128, glb_t,128, g_f,1024, glbias, 3, 128);

  // 7. kk normalize + k update
  k_scanprep<<<16384, 256, 0, stream>>>(k_f, a_f, k_k, k_a, kk_f);

  // 8. sequential scan -> o (in d_out)
  k_scan<<<32, 512, 0, stream>>>(r_f, ew_f, k_f, v_f, kk_f, a_f, oF);

  // 9. groupnorm + bonus + gate -> y_f
  k_post<<<16384, 256, 0, stream>>>(oF, r_f, k_f, v_f, r_k, gnw, gnb, g_f, y_f);

  // 10. output projection (overwrites d_out)
  k_gemm_split<<<dim3(32,8), 256, 0, stream>>>(y_f,1024, Wo_t,1024, (float*)d_out,1024, nullptr, 0, 1024);
}

// Round 3
// 1212.511 us; speedup vs baseline: 1.3727x; 1.3727x over previous
//
#include <hip/hip_runtime.h>
#include <hip/hip_bf16.h>
#include <stdint.h>
#include <stddef.h>

typedef __hip_bfloat16 bf16;
typedef __attribute__((ext_vector_type(8))) short short8;
typedef __attribute__((ext_vector_type(4))) float f32x4;

__device__ __forceinline__ float dsigm(float z){ return 1.f/(1.f+expf(-z)); }

// split fp32 -> hi (bit-truncated bf16) + lo (rounded bf16 residual); hi+lo ~ 16 mantissa bits
__device__ __forceinline__ void split1(float v, unsigned short& h, unsigned short& l) {
  unsigned int u = __builtin_bit_cast(unsigned int, v);
  h = (unsigned short)(u >> 16);
  float hf = __builtin_bit_cast(float, u & 0xFFFF0000u);
  bf16 lb = __float2bfloat16(v - hf);
  l = __builtin_bit_cast(unsigned short, lb);
}

// split 8 contiguous floats into hi/lo short8 fragments
__device__ __forceinline__ void split8(const float* f, short8& h, short8& l) {
#pragma unroll
  for (int e = 0; e < 8; ++e) {
    unsigned short hh, ll;
    split1(f[e], hh, ll);
    h[e] = (short)hh; l[e] = (short)ll;
  }
}

//==================== 1. time-shift lerp -> fp32 operands ====================
__global__ void k_prep(const float* __restrict__ hs,
    const float* __restrict__ mr, const float* __restrict__ mw, const float* __restrict__ mk,
    const float* __restrict__ mv, const float* __restrict__ ma,
    float* __restrict__ oxr, float* __restrict__ oxw, float* __restrict__ oxk,
    float* __restrict__ oxv, float* __restrict__ oxa)
{
  size_t id = (size_t)blockIdx.x*256u + threadIdx.x;
  if (id >= (size_t)4194304) return;
  int c = (int)(id & 1023);
  int t = (int)((id >> 10) & 2047);
  float cur = hs[id];
  float prev = (t > 0) ? hs[id - 1024] : 0.f;
  float d = prev - cur;
  oxr[id] = fmaf(d, mr[c], cur);
  oxw[id] = fmaf(d, mw[c], cur);
  oxk[id] = fmaf(d, mk[c], cur);
  oxv[id] = fmaf(d, mv[c], cur);
  oxa[id] = fmaf(d, ma[c], cur);
}

//==================== 2. weight transpose (fp32) ====================
struct SrcP { const float* p[10]; };
struct DstP { float* p[10]; };

__global__ void k_transpose(SrcP S, DstP Dd)
{
  static constexpr int TR[10]  = {1024,1024,1024,1024,1024,  64,1024,  64,1024, 128};
  static constexpr int TCC[10] = {1024,1024,1024,1024,  64,1024,  64,1024, 128,1024};
  static constexpr int TCP[10] = {1024,1024,1024,1024, 128,1024, 128,1024, 128,1024};
  int z = blockIdx.z;
  int R = TR[z], Cc = TCC[z], Cp = TCP[z];
  int n0 = blockIdx.x * 32, r0 = blockIdx.y * 32;
  if (n0 >= Cp || r0 >= R) return;
  const float* src = S.p[z];
  float* dst = Dd.p[z];
  int tx = threadIdx.x, ty = threadIdx.y;
  __shared__ float tile[32][33];
  if (n0 < Cc) {
#pragma unroll
    for (int i = 0; i < 4; ++i)
      tile[ty + 8*i][tx] = src[(size_t)(r0 + ty + 8*i)*Cc + n0 + tx];
    __syncthreads();
#pragma unroll
    for (int i = 0; i < 4; ++i)
      dst[(size_t)(n0 + ty + 8*i)*R + r0 + tx] = tile[tx][ty + 8*i];
  } else {
#pragma unroll
    for (int i = 0; i < 4; ++i)
      dst[(size_t)(n0 + ty + 8*i)*R + r0 + tx] = 0.f;
  }
}

//==================== 3. split-bf16 MFMA GEMM (fp32-accurate) ====================
// C[M][N] = A[M][K] (fp32) * Bt[N][K]^T (fp32). tile 128x128, BK=32, 4 waves.
// mode: 0 none | 1 ew=e^-0.5*sigmoid(x+bias) | 2 sigmoid(x+bias) | 3 x+bias
__global__ __launch_bounds__(256) void k_gemm_split(
    const float* __restrict__ A, int lda,
    const float* __restrict__ Bt, int ldb,
    float* __restrict__ C, int ldc,
    const float* __restrict__ bias, int mode, int K)
{
  __shared__ __align__(16) unsigned short AsH[128*32];
  __shared__ __align__(16) unsigned short AsL[128*32];
  __shared__ __align__(16) unsigned short BsH[128*32];
  __shared__ __align__(16) unsigned short BsL[128*32];
  const int tid = threadIdx.x;
  const int l = tid & 63, w = tid >> 6;
  const int wm = w >> 1, wn = w & 1;
  const int rowBase = blockIdx.x * 128, colBase = blockIdx.y * 128;
  const int lrow = l & 15, kid = (l >> 4) * 8;

  f32x4 acc[4][4];
#pragma unroll
  for (int i = 0; i < 4; ++i)
#pragma unroll
    for (int j = 0; j < 4; ++j) { f32x4 z = {0.f,0.f,0.f,0.f}; acc[i][j] = z; }

  const int nk = K >> 5;
  for (int kt = 0; kt < nk; ++kt) {
#pragma unroll
    for (int rr = 0; rr < 4; ++rr) {
      int idx = rr*256 + tid;
      int ar = idx >> 3, ac = (idx & 7) * 4;
      float4 va = *(const float4*)(A  + (size_t)(rowBase + ar)*lda + kt*32 + ac);
      float4 vb = *(const float4*)(Bt + (size_t)(colBase + ar)*ldb + kt*32 + ac);
      ushort4 ha, la, hb, lb;
      split1(va.x, ha.x, la.x); split1(va.y, ha.y, la.y);
      split1(va.z, ha.z, la.z); split1(va.w, ha.w, la.w);
      split1(vb.x, hb.x, lb.x); split1(vb.y, hb.y, lb.y);
      split1(vb.z, hb.z, lb.z); split1(vb.w, hb.w, lb.w);
      *(ushort4*)&AsH[ar*32 + ac] = ha;
      *(ushort4*)&AsL[ar*32 + ac] = la;
      *(ushort4*)&BsH[ar*32 + ac] = hb;
      *(ushort4*)&BsL[ar*32 + ac] = lb;
    }
    __syncthreads();
    short8 fah[4], fal[4], fbh[4], fbl[4];
#pragma unroll
    for (int mt = 0; mt < 4; ++mt) {
      int ro = (wm*64 + mt*16 + lrow)*32 + kid;
      fah[mt] = *(const short8*)&AsH[ro];
      fal[mt] = *(const short8*)&AsL[ro];
    }
#pragma unroll
    for (int nt = 0; nt < 4; ++nt) {
      int ro = (wn*64 + nt*16 + lrow)*32 + kid;
      fbh[nt] = *(const short8*)&BsH[ro];
      fbl[nt] = *(const short8*)&BsL[ro];
    }
#pragma unroll
    for (int mt = 0; mt < 4; ++mt)
#pragma unroll
      for (int nt = 0; nt < 4; ++nt) {
        acc[mt][nt] = __builtin_amdgcn_mfma_f32_16x16x32_bf16(fah[mt], fbh[nt], acc[mt][nt], 0, 0, 0);
        acc[mt][nt] = __builtin_amdgcn_mfma_f32_16x16x32_bf16(fal[mt], fbh[nt], acc[mt][nt], 0, 0, 0);
        acc[mt][nt] = __builtin_amdgcn_mfma_f32_16x16x32_bf16(fah[mt], fbl[nt], acc[mt][nt], 0, 0, 0);
      }
    __syncthreads();
  }
#pragma unroll
  for (int mt = 0; mt < 4; ++mt) {
    int row = rowBase + wm*64 + mt*16 + (l >> 4)*4;
#pragma unroll
    for (int nt = 0; nt < 4; ++nt) {
      int col = colBase + wn*64 + nt*16 + (l & 15);
      float bv = (bias != nullptr) ? bias[col] : 0.f;
#pragma unroll
      for (int rg = 0; rg < 4; ++rg) {
        float v = acc[mt][nt][rg];
        if (mode == 1)      v = 0.60653066f * dsigm(v + bv);
        else if (mode == 2) v = dsigm(v + bv);
        else if (mode == 3) v = v + bv;
        C[(size_t)(row + rg)*ldc + col] = v;
      }
    }
  }
}

//==================== 4. activation between LoRA stages ====================
__global__ void k_act(const float* __restrict__ in, float* __restrict__ out, int logc, int mode)
{
  int id = blockIdx.x * 256 + threadIdx.x;
  int r = id >> logc, c = id & ((1 << logc) - 1);
  float v = in[r * 128 + c];
  if (mode == 1) v = tanhf(v);
  else if (mode == 2) v = dsigm(v);
  out[id] = v;
}

//==================== 5. scan prep: kk normalize + k update + b=kk*a ====================
__global__ void k_scanprep(float* __restrict__ kA, float* __restrict__ aA,
                           const float* __restrict__ kkw, const float* __restrict__ kaw,
                           float* __restrict__ kkA)
{
  size_t gt = (size_t)blockIdx.x * 256u + threadIdx.x;
  int d = (int)(gt & 63);
  size_t flat = gt >> 6;
  int c = (int)((flat & 15) * 64 + d);
  float k0 = kA[gt], av = aA[gt];
  float kkv = k0 * kkw[c];
  float ss = kkv * kkv;
  ss += __shfl_xor(ss, 1);  ss += __shfl_xor(ss, 2);  ss += __shfl_xor(ss, 4);
  ss += __shfl_xor(ss, 8);  ss += __shfl_xor(ss, 16); ss += __shfl_xor(ss, 32);
  float inv = 1.f / fmaxf(sqrtf(ss), 1e-12f);
  float kkn = kkv * inv;
  kkA[gt] = kkn;               // a_scan = -kkn (negation applied in-kernel)
  aA[gt]  = kkn * av;          // b_scan = kkn * a_head (overwrites a_head, no longer needed)
  kA[gt]  = k0 * fmaf(av - 1.f, kaw[c], 1.f);
}

//==================== 6a. chunked scan pass 1 ====================
// Per (bh, chunk): run recurrence from U=0 and P=I over L=64 steps.
// Emits o0_t = U_t r_t, z_t = P_t r_t, chunk-end U_c and P_c^T.
struct Step2 { float4 ew[2], kk[2], bb[2], kv[2], rr[2]; float vi; };

__device__ __forceinline__ void load_step2(Step2& d,
    const float* __restrict__ ewA, const float* __restrict__ kkA, const float* __restrict__ bbA,
    const float* __restrict__ kA, const float* __restrict__ rA, const float* __restrict__ vA,
    size_t base, int j0, int i)
{
  d.ew[0] = *(const float4*)(ewA + base + j0); d.ew[1] = *(const float4*)(ewA + base + j0 + 4);
  d.kk[0] = *(const float4*)(kkA + base + j0); d.kk[1] = *(const float4*)(kkA + base + j0 + 4);
  d.bb[0] = *(const float4*)(bbA + base + j0); d.bb[1] = *(const float4*)(bbA + base + j0 + 4);
  d.kv[0] = *(const float4*)(kA  + base + j0); d.kv[1] = *(const float4*)(kA  + base + j0 + 4);
  d.rr[0] = *(const float4*)(rA  + base + j0); d.rr[1] = *(const float4*)(rA  + base + j0 + 4);
  d.vi = vA[base + i];
}

__device__ __forceinline__ void step2_compute(const Step2& d, float* u, float* p,
    float* __restrict__ o0A, float* __restrict__ zA, size_t base, int i, int q)
{
  float uk = 0.f, pk = 0.f;
#define RED(SI, U, F) { uk += u[SI]*d.kk[U].F; pk += p[SI]*d.kk[U].F; }
  RED(0,0,x) RED(1,0,y) RED(2,0,z) RED(3,0,w)
  RED(4,1,x) RED(5,1,y) RED(6,1,z) RED(7,1,w)
#undef RED
  uk += __shfl_xor(uk, 1); uk += __shfl_xor(uk, 2); uk += __shfl_xor(uk, 4);
  pk += __shfl_xor(pk, 1); pk += __shfl_xor(pk, 2); pk += __shfl_xor(pk, 4);
  const float su = -uk, sp = -pk, vi = d.vi;
  float oo = 0.f, zz = 0.f;
#define UPD(SI, U, F) { \
    float uu = u[SI]*d.ew[U].F + su*d.bb[U].F + vi*d.kv[U].F; u[SI] = uu; oo += uu*d.rr[U].F; \
    float pp = p[SI]*d.ew[U].F + sp*d.bb[U].F;               p[SI] = pp; zz += pp*d.rr[U].F; }
  UPD(0,0,x) UPD(1,0,y) UPD(2,0,z) UPD(3,0,w)
  UPD(4,1,x) UPD(5,1,y) UPD(6,1,z) UPD(7,1,w)
#undef UPD
  oo += __shfl_xor(oo, 1); oo += __shfl_xor(oo, 2); oo += __shfl_xor(oo, 4);
  zz += __shfl_xor(zz, 1); zz += __shfl_xor(zz, 2); zz += __shfl_xor(zz, 4);
  if (q == 0) { o0A[base + i] = oo; zA[base + i] = zz; }
}

__global__ __launch_bounds__(512) void k_scan_p1(
    const float* __restrict__ rA, const float* __restrict__ ewA,
    const float* __restrict__ kA, const float* __restrict__ vA,
    const float* __restrict__ kkA, const float* __restrict__ bbA,
    float* __restrict__ o0A, float* __restrict__ zA,
    float* __restrict__ UcA, float* __restrict__ PTcA)
{
  const int blk = blockIdx.x;
  const int bh = blk & 31, c = blk >> 5;     // chunk-major: neighbors share t-rows
  const int b = bh >> 4, h = bh & 15;
  const int tid = threadIdx.x;
  const int i = tid >> 3, q = tid & 7, j0 = q * 8;
  const size_t base0 = (size_t)b*2048*1024 + (size_t)h*64 + (size_t)(c*64)*1024;
  float u[8], p[8];
#pragma unroll
  for (int jj = 0; jj < 8; ++jj) { u[jj] = 0.f; p[jj] = (j0 + jj == i) ? 1.f : 0.f; }

  Step2 d0, d1;
  load_step2(d0, ewA,kkA,bbA,kA,rA,vA, base0,        j0, i);
  load_step2(d1, ewA,kkA,bbA,kA,rA,vA, base0 + 1024, j0, i);
  for (int tl = 0; tl < 64; tl += 2) {
    step2_compute(d0, u, p, o0A, zA, base0 + (size_t)tl*1024, i, q);
    if (tl + 2 < 64) load_step2(d0, ewA,kkA,bbA,kA,rA,vA, base0 + (size_t)(tl+2)*1024, j0, i);
    step2_compute(d1, u, p, o0A, zA, base0 + (size_t)(tl+1)*1024, i, q);
    if (tl + 3 < 64) load_step2(d1, ewA,kkA,bbA,kA,rA,vA, base0 + (size_t)(tl+3)*1024, j0, i);
  }

  // store U_c (row-major [i][j]) and P_c^T (row-major [j][m]) for pass 2
  const size_t cbase = ((size_t)(bh*32 + c)) * 4096;
  *(float4*)(UcA + cbase + (size_t)i*64 + j0)     = make_float4(u[0],u[1],u[2],u[3]);
  *(float4*)(UcA + cbase + (size_t)i*64 + j0 + 4) = make_float4(u[4],u[5],u[6],u[7]);
  __shared__ float lds[64][65];
#pragma unroll
  for (int jj = 0; jj < 8; ++jj) lds[i][j0 + jj] = p[jj];
  __syncthreads();
  float4 w0 = make_float4(lds[j0+0][i], lds[j0+1][i], lds[j0+2][i], lds[j0+3][i]);
  float4 w1 = make_float4(lds[j0+4][i], lds[j0+5][i], lds[j0+6][i], lds[j0+7][i]);
  *(float4*)(PTcA + cbase + (size_t)i*64 + j0)     = w0;
  *(float4*)(PTcA + cbase + (size_t)i*64 + j0 + 4) = w1;
}

//==================== 6b. pass 2: state chain + output correction ====================
// One wave per (b,h). Iterate chunks: o[chunk c] += Z_c @ S^T ; S = S @ P_c + U_c.
// Split-bf16 (3-term) MFMA keeps fp32-level accuracy.
__global__ __launch_bounds__(64) void k_pass2(
    const float* __restrict__ UcA, const float* __restrict__ PTcA,
    const float* __restrict__ zA, float* __restrict__ oA)
{
  const int bh = blockIdx.x, b = bh >> 4, h = bh & 15;
  const int l = threadIdx.x;
  const int lr = l & 15, lq = l >> 4;
  __shared__ float Slds[64][65];

  f32x4 acc[4][4];
#pragma unroll
  for (int mt = 0; mt < 4; ++mt)
#pragma unroll
    for (int nt = 0; nt < 4; ++nt) { f32x4 z = {0.f,0.f,0.f,0.f}; acc[mt][nt] = z; }

  for (int c = 0; c < 32; ++c) {
    // (a) current S (= S0 for chunk c) -> LDS
#pragma unroll
    for (int mt = 0; mt < 4; ++mt)
#pragma unroll
      for (int nt = 0; nt < 4; ++nt)
#pragma unroll
        for (int rg = 0; rg < 4; ++rg)
          Slds[mt*16 + lq*4 + rg][nt*16 + lr] = acc[mt][nt][rg];

    // (b) output correction: o[c*64+tl][i] += sum_m Z[tl][m] * S0[i][m]
    if (c > 0) {
      short8 sbh[4][2], sbl[4][2];
#pragma unroll
      for (int nt = 0; nt < 4; ++nt)
#pragma unroll
        for (int kt = 0; kt < 2; ++kt) {
          float f[8];
#pragma unroll
          for (int e = 0; e < 8; ++e) f[e] = Slds[nt*16 + lr][kt*32 + lq*8 + e];
          split8(f, sbh[nt][kt], sbl[nt][kt]);
        }
#pragma unroll
      for (int mt = 0; mt < 4; ++mt) {
        short8 zh[2], zl[2];
#pragma unroll
        for (int kt = 0; kt < 2; ++kt) {
          const float* zp = zA + ((size_t)(b*2048 + c*64 + mt*16 + lr)*16 + h)*64 + kt*32 + lq*8;
          float f[8];
#pragma unroll
          for (int e = 0; e < 8; ++e) f[e] = zp[e];
          split8(f, zh[kt], zl[kt]);
        }
        f32x4 a2[4];
#pragma unroll
        for (int nt = 0; nt < 4; ++nt) { f32x4 z = {0.f,0.f,0.f,0.f}; a2[nt] = z; }
#pragma unroll
        for (int kt = 0; kt < 2; ++kt)
#pragma unroll
          for (int nt = 0; nt < 4; ++nt) {
            a2[nt] = __builtin_amdgcn_mfma_f32_16x16x32_bf16(zh[kt], sbh[nt][kt], a2[nt], 0, 0, 0);
            a2[nt] = __builtin_amdgcn_mfma_f32_16x16x32_bf16(zl[kt], sbh[nt][kt], a2[nt], 0, 0, 0);
            a2[nt] = __builtin_amdgcn_mfma_f32_16x16x32_bf16(zh[kt], sbl[nt][kt], a2[nt], 0, 0, 0);
          }
#pragma unroll
        for (int nt = 0; nt < 4; ++nt)
#pragma unroll
          for (int rg = 0; rg < 4; ++rg) {
            int tl = mt*16 + lq*4 + rg, ii = nt*16 + lr;
            size_t ad = ((size_t)(b*2048 + c*64 + tl)*16 + h)*64 + ii;
            oA[ad] += a2[nt][rg];
          }
      }
    }

    // (c) S = U_c + S_prev @ P_c   (A-frags from LDS, B-frags from PT_c)
    const size_t cbase = ((size_t)(bh*32 + c)) * 4096;
#pragma unroll
    for (int mt = 0; mt < 4; ++mt)
#pragma unroll
      for (int nt = 0; nt < 4; ++nt)
#pragma unroll
        for (int rg = 0; rg < 4; ++rg)
          acc[mt][nt][rg] = UcA[cbase + (size_t)(mt*16 + lq*4 + rg)*64 + nt*16 + lr];
    short8 pbh[4][2], pbl[4][2];
#pragma unroll
    for (int nt = 0; nt < 4; ++nt)
#pragma unroll
      for (int kt = 0; kt < 2; ++kt) {
        const float* pp = PTcA + cbase + (size_t)(nt*16 + lr)*64 + kt*32 + lq*8;
        float f[8];
#pragma unroll
        for (int e = 0; e < 8; ++e) f[e] = pp[e];
        split8(f, pbh[nt][kt], pbl[nt][kt]);
      }
#pragma unroll
    for (int mt = 0; mt < 4; ++mt)
#pragma unroll
      for (int kt = 0; kt < 2; ++kt) {
        float f[8];
#pragma unroll
        for (int e = 0; e < 8; ++e) f[e] = Slds[mt*16 + lr][kt*32 + lq*8 + e];
        short8 sah, sal;
        split8(f, sah, sal);
#pragma unroll
        for (int nt = 0; nt < 4; ++nt) {
          acc[mt][nt] = __builtin_amdgcn_mfma_f32_16x16x32_bf16(sah, pbh[nt][kt], acc[mt][nt], 0, 0, 0);
          acc[mt][nt] = __builtin_amdgcn_mfma_f32_16x16x32_bf16(sal, pbh[nt][kt], acc[mt][nt], 0, 0, 0);
          acc[mt][nt] = __builtin_amdgcn_mfma_f32_16x16x32_bf16(sah, pbl[nt][kt], acc[mt][nt], 0, 0, 0);
        }
      }
  }
}

//==================== 7. GroupNorm + bonus + gate (fp32) ====================
__global__ void k_post(const float* __restrict__ oA, const float* __restrict__ rA,
    const float* __restrict__ kA, const float* __restrict__ vA,
    const float* __restrict__ rk, const float* __restrict__ gnw, const float* __restrict__ gnb,
    const float* __restrict__ gA, float* __restrict__ yA)
{
  size_t gt = (size_t)blockIdx.x * 256u + threadIdx.x;
  int d = (int)(gt & 63);
  size_t flat = gt >> 6;
  int c = (int)((flat & 15) * 64 + d);
  float ov = oA[gt];
  float ss = ov;
  ss += __shfl_xor(ss, 1);  ss += __shfl_xor(ss, 2);  ss += __shfl_xor(ss, 4);
  ss += __shfl_xor(ss, 8);  ss += __shfl_xor(ss, 16); ss += __shfl_xor(ss, 32);
  float mean = ss * (1.f/64.f);
  float dm = ov - mean;
  float vv = dm * dm;
  vv += __shfl_xor(vv, 1);  vv += __shfl_xor(vv, 2);  vv += __shfl_xor(vv, 4);
  vv += __shfl_xor(vv, 8);  vv += __shfl_xor(vv, 16); vv += __shfl_xor(vv, 32);
  float var = vv * (1.f/64.f);
  float y = dm * rsqrtf(var + 1e-5f) * gnw[c] + gnb[c];
  float pr = rA[gt] * kA[gt] * rk[c];
  pr += __shfl_xor(pr, 1);  pr += __shfl_xor(pr, 2);  pr += __shfl_xor(pr, 4);
  pr += __shfl_xor(pr, 8);  pr += __shfl_xor(pr, 16); pr += __shfl_xor(pr, 32);
  y += pr * vA[gt];
  y *= gA[gt];
  yA[gt] = y;
}

//==================== host ====================
extern "C" void kernel_launch(void* const* d_in, const int* in_sizes, int n_in,
                              void* d_out, int out_size, void* d_ws, size_t ws_size,
                              hipStream_t stream)
{
  (void)in_sizes; (void)n_in; (void)out_size; (void)ws_size;
  const float* hs     = (const float*)d_in[0];
  const float* x_r    = (const float*)d_in[1];
  const float* x_w    = (const float*)d_in[2];
  const float* x_k    = (const float*)d_in[3];
  const float* x_v    = (const float*)d_in[4];
  const float* x_a    = (const float*)d_in[5];
  const float* k_k    = (const float*)d_in[7];
  const float* k_a    = (const float*)d_in[8];
  const float* r_k    = (const float*)d_in[9];
  const float* W_r    = (const float*)d_in[10];
  const float* W_k    = (const float*)d_in[11];
  const float* W_v    = (const float*)d_in[12];
  const float* W_o    = (const float*)d_in[13];
  const float* wla    = (const float*)d_in[14];
  const float* wlb    = (const float*)d_in[15];
  const float* wlbias = (const float*)d_in[16];
  const float* ala    = (const float*)d_in[17];
  const float* alb    = (const float*)d_in[18];
  const float* albias = (const float*)d_in[19];
  const float* gla    = (const float*)d_in[20];
  const float* glb    = (const float*)d_in[21];
  const float* glbias = (const float*)d_in[22];
  const float* gnw    = (const float*)d_in[23];
  const float* gnb    = (const float*)d_in[24];

  char* ws = (char*)d_ws;
  constexpr size_t MB = 1024u*1024u;
  size_t cur = 0;
  auto take = [&](size_t bytes) { size_t o = cur; cur += (bytes + 255) & ~(size_t)255; return o; };

  float* xr_f = (float*)(ws + take(16*MB));
  float* xw_f = (float*)(ws + take(16*MB));
  float* xk_f = (float*)(ws + take(16*MB));
  float* xv_f = (float*)(ws + take(16*MB));
  float* xa_f = (float*)(ws + take(16*MB));
  float* Wr_t  = (float*)(ws + take(4*MB));
  float* Wk_t  = (float*)(ws + take(4*MB));
  float* Wv_t  = (float*)(ws + take(4*MB));
  float* Wo_t  = (float*)(ws + take(4*MB));
  float* wla_t = (float*)(ws + take(128*1024*4));
  float* wlb_t = (float*)(ws + take(1024*64*4));
  float* ala_t = (float*)(ws + take(128*1024*4));
  float* alb_t = (float*)(ws + take(1024*64*4));
  float* gla_t = (float*)(ws + take(128*1024*4));
  float* glb_t = (float*)(ws + take(1024*128*4));
  float* r_f  = (float*)(ws + take(16*MB));
  float* k_f  = (float*)(ws + take(16*MB));
  float* v_f  = (float*)(ws + take(16*MB));
  float* t1   = (float*)(ws + take(2*MB));
  float* t2   = (float*)(ws + take(2*MB));
  float* z_f  = (float*)(ws + take(16*MB));      // z_t = P_t r_t, layout (b,t,h,m)
  float* Uc_f = (float*)(ws + take(16*MB));      // [bh][32][64][64]
  float* PT_f = (float*)(ws + take(16*MB));      // [bh][32][64][64] (P^T)
  // aliases (lifetime-checked against launch order):
  float* ew_f = xr_f;   // xr consumed by r-GEMM before ew written
  float* a_f  = xk_f;   // xk consumed by k-GEMM; holds a then b=kk*a
  float* kk_f = xw_f;   // xw consumed by w-LoRA stage1
  float* g_f  = xv_f;   // xv consumed by v-GEMM
  float* y_f  = xa_f;   // xa consumed by a-LoRA stage1
  float* oF   = (float*)d_out;

  // 1. prep
  k_prep<<<16384, 256, 0, stream>>>(hs, x_r, x_w, x_k, x_v, x_a,
                                    xr_f, xw_f, xk_f, xv_f, xa_f);
  // 2. weight transposes
  SrcP sp; DstP dp;
  sp.p[0]=W_r; sp.p[1]=W_k; sp.p[2]=W_v; sp.p[3]=W_o;
  sp.p[4]=wla; sp.p[5]=wlb; sp.p[6]=ala; sp.p[7]=alb; sp.p[8]=gla; sp.p[9]=glb;
  dp.p[0]=Wr_t; dp.p[1]=Wk_t; dp.p[2]=Wv_t; dp.p[3]=Wo_t;
  dp.p[4]=wla_t; dp.p[5]=wlb_t; dp.p[6]=ala_t; dp.p[7]=alb_t; dp.p[8]=gla_t; dp.p[9]=glb_t;
  k_transpose<<<dim3(32,32,10), dim3(32,8), 0, stream>>>(sp, dp);

  // 3. big projections
  k_gemm_split<<<dim3(32,8), 256, 0, stream>>>(xr_f,1024, Wr_t,1024, r_f,1024, nullptr, 0, 1024);
  k_gemm_split<<<dim3(32,8), 256, 0, stream>>>(xk_f,1024, Wk_t,1024, k_f,1024, nullptr, 0, 1024);
  k_gemm_split<<<dim3(32,8), 256, 0, stream>>>(xv_f,1024, Wv_t,1024, v_f,1024, nullptr, 0, 1024);

  // 4. w-LoRA
  k_gemm_split<<<dim3(32,1), 256, 0, stream>>>(xw_f,1024, wla_t,1024, t1,128, nullptr, 0, 1024);
  k_act<<<1024, 256, 0, stream>>>(t1, t2, 6, 1);
  k_gemm_split<<<dim3(32,8), 256, 0, stream>>>(t2,64, wlb_t,64, ew_f,1024, wlbias, 1, 64);

  // 5. a-LoRA
  k_gemm_split<<<dim3(32,1), 256, 0, stream>>>(xa_f,1024, ala_t,1024, t1,128, nullptr, 0, 1024);
  k_act<<<1024, 256, 0, stream>>>(t1, t2, 6, 0);
  k_gemm_split<<<dim3(32,8), 256, 0, stream>>>(t2,64, alb_t,64, a_f,1024, albias, 2, 64);

  // 6. g-LoRA
  k_gemm_split<<<dim3(32,1), 256, 0, stream>>>(r_f,1024, gla_t,1024, t1,128, nullptr, 0, 1024);
  k_act<<<2048, 256, 0, stream>>>(t1, t2, 7, 2);
  k_gemm_split<<<dim3(32,8), 256, 0, stream>>>(t2,128, glb_t,128, g_f,1024, glbias, 3, 128);

  // 7. kk normalize + k update + b precompute
  k_scanprep<<<16384, 256, 0, stream>>>(k_f, a_f, k_k, k_a, kk_f);

  // 8. chunked scan: pass 1 (parallel over 32 chunks x 32 bh)
  k_scan_p1<<<1024, 512, 0, stream>>>(r_f, ew_f, k_f, v_f, kk_f, a_f, oF, z_f, Uc_f, PT_f);
  //    pass 2: sequential chunk chain + output correction (32 waves)
  k_pass2<<<32, 64, 0, stream>>>(Uc_f, PT_f, z_f, oF);

  // 9. groupnorm + bonus + gate
  k_post<<<16384, 256, 0, stream>>>(oF, r_f, k_f, v_f, r_k, gnw, gnb, g_f, y_f);

  // 10. output projection (overwrites d_out)
  k_gemm_split<<<dim3(32,8), 256, 0, stream>>>(y_f,1024, Wo_t,1024, (float*)d_out,1024, nullptr, 0, 1024);
}

// Round 4
// 708.546 us; speedup vs baseline: 2.3490x; 1.7113x over previous
//
#include <hip/hip_runtime.h>
#include <hip/hip_bf16.h>
#include <stdint.h>
#include <stddef.h>

typedef __hip_bfloat16 bf16;
typedef __attribute__((ext_vector_type(8))) short short8;
typedef __attribute__((ext_vector_type(4))) float f32x4;

__device__ __forceinline__ float dsigm(float z){ return 1.f/(1.f+expf(-z)); }

// split fp32 -> hi (bit-truncated bf16) + lo (rounded bf16 residual); hi+lo ~ 16 mantissa bits
__device__ __forceinline__ void split1(float v, unsigned short& h, unsigned short& l) {
  unsigned int u = __builtin_bit_cast(unsigned int, v);
  h = (unsigned short)(u >> 16);
  float hf = __builtin_bit_cast(float, u & 0xFFFF0000u);
  bf16 lb = __float2bfloat16(v - hf);
  l = __builtin_bit_cast(unsigned short, lb);
}

__device__ __forceinline__ void split8(const float* f, short8& h, short8& l) {
#pragma unroll
  for (int e = 0; e < 8; ++e) {
    unsigned short hh, ll;
    split1(f[e], hh, ll);
    h[e] = (short)hh; l[e] = (short)ll;
  }
}

//==================== 1. time-shift lerp -> fp32 operands ====================
__global__ void k_prep(const float* __restrict__ hs,
    const float* __restrict__ mr, const float* __restrict__ mw, const float* __restrict__ mk,
    const float* __restrict__ mv, const float* __restrict__ ma,
    float* __restrict__ oxr, float* __restrict__ oxw, float* __restrict__ oxk,
    float* __restrict__ oxv, float* __restrict__ oxa)
{
  size_t id = (size_t)blockIdx.x*256u + threadIdx.x;
  if (id >= (size_t)4194304) return;
  int c = (int)(id & 1023);
  int t = (int)((id >> 10) & 2047);
  float cur = hs[id];
  float prev = (t > 0) ? hs[id - 1024] : 0.f;
  float d = prev - cur;
  oxr[id] = fmaf(d, mr[c], cur);
  oxw[id] = fmaf(d, mw[c], cur);
  oxk[id] = fmaf(d, mk[c], cur);
  oxv[id] = fmaf(d, mv[c], cur);
  oxa[id] = fmaf(d, ma[c], cur);
}

//==================== 2. weight transpose (fp32) ====================
struct SrcP { const float* p[10]; };
struct DstP { float* p[10]; };

__global__ void k_transpose(SrcP S, DstP Dd)
{
  static constexpr int TR[10]  = {1024,1024,1024,1024,1024,  64,1024,  64,1024, 128};
  static constexpr int TCC[10] = {1024,1024,1024,1024,  64,1024,  64,1024, 128,1024};
  static constexpr int TCP[10] = {1024,1024,1024,1024, 128,1024, 128,1024, 128,1024};
  int z = blockIdx.z;
  int R = TR[z], Cc = TCC[z], Cp = TCP[z];
  int n0 = blockIdx.x * 32, r0 = blockIdx.y * 32;
  if (n0 >= Cp || r0 >= R) return;
  const float* src = S.p[z];
  float* dst = Dd.p[z];
  int tx = threadIdx.x, ty = threadIdx.y;
  __shared__ float tile[32][33];
  if (n0 < Cc) {
#pragma unroll
    for (int i = 0; i < 4; ++i)
      tile[ty + 8*i][tx] = src[(size_t)(r0 + ty + 8*i)*Cc + n0 + tx];
    __syncthreads();
#pragma unroll
    for (int i = 0; i < 4; ++i)
      dst[(size_t)(n0 + ty + 8*i)*R + r0 + tx] = tile[tx][ty + 8*i];
  } else {
#pragma unroll
    for (int i = 0; i < 4; ++i)
      dst[(size_t)(n0 + ty + 8*i)*R + r0 + tx] = 0.f;
  }
}

//==================== 3. split-bf16 MFMA GEMM (fp32-accurate) ====================
// C[M][N] = A[M][K] (fp32) * Bt[N][K]^T (fp32). tile 128x128, BK=32, 4 waves.
// mode: 0 none | 1 ew=e^-0.5*sigmoid(x+bias) | 2 sigmoid(x+bias) | 3 x+bias
__global__ __launch_bounds__(256) void k_gemm_split(
    const float* __restrict__ A, int lda,
    const float* __restrict__ Bt, int ldb,
    float* __restrict__ C, int ldc,
    const float* __restrict__ bias, int mode, int K)
{
  __shared__ __align__(16) unsigned short AsH[128*32];
  __shared__ __align__(16) unsigned short AsL[128*32];
  __shared__ __align__(16) unsigned short BsH[128*32];
  __shared__ __align__(16) unsigned short BsL[128*32];
  const int tid = threadIdx.x;
  const int l = tid & 63, w = tid >> 6;
  const int wm = w >> 1, wn = w & 1;
  const int rowBase = blockIdx.x * 128, colBase = blockIdx.y * 128;
  const int lrow = l & 15, kid = (l >> 4) * 8;

  f32x4 acc[4][4];
#pragma unroll
  for (int i = 0; i < 4; ++i)
#pragma unroll
    for (int j = 0; j < 4; ++j) { f32x4 z = {0.f,0.f,0.f,0.f}; acc[i][j] = z; }

  const int nk = K >> 5;
  for (int kt = 0; kt < nk; ++kt) {
#pragma unroll
    for (int rr = 0; rr < 4; ++rr) {
      int idx = rr*256 + tid;
      int ar = idx >> 3, ac = (idx & 7) * 4;
      float4 va = *(const float4*)(A  + (size_t)(rowBase + ar)*lda + kt*32 + ac);
      float4 vb = *(const float4*)(Bt + (size_t)(colBase + ar)*ldb + kt*32 + ac);
      ushort4 ha, la, hb, lb;
      split1(va.x, ha.x, la.x); split1(va.y, ha.y, la.y);
      split1(va.z, ha.z, la.z); split1(va.w, ha.w, la.w);
      split1(vb.x, hb.x, lb.x); split1(vb.y, hb.y, lb.y);
      split1(vb.z, hb.z, lb.z); split1(vb.w, hb.w, lb.w);
      *(ushort4*)&AsH[ar*32 + ac] = ha;
      *(ushort4*)&AsL[ar*32 + ac] = la;
      *(ushort4*)&BsH[ar*32 + ac] = hb;
      *(ushort4*)&BsL[ar*32 + ac] = lb;
    }
    __syncthreads();
    short8 fah[4], fal[4], fbh[4], fbl[4];
#pragma unroll
    for (int mt = 0; mt < 4; ++mt) {
      int ro = (wm*64 + mt*16 + lrow)*32 + kid;
      fah[mt] = *(const short8*)&AsH[ro];
      fal[mt] = *(const short8*)&AsL[ro];
    }
#pragma unroll
    for (int nt = 0; nt < 4; ++nt) {
      int ro = (wn*64 + nt*16 + lrow)*32 + kid;
      fbh[nt] = *(const short8*)&BsH[ro];
      fbl[nt] = *(const short8*)&BsL[ro];
    }
#pragma unroll
    for (int mt = 0; mt < 4; ++mt)
#pragma unroll
      for (int nt = 0; nt < 4; ++nt) {
        acc[mt][nt] = __builtin_amdgcn_mfma_f32_16x16x32_bf16(fah[mt], fbh[nt], acc[mt][nt], 0, 0, 0);
        acc[mt][nt] = __builtin_amdgcn_mfma_f32_16x16x32_bf16(fal[mt], fbh[nt], acc[mt][nt], 0, 0, 0);
        acc[mt][nt] = __builtin_amdgcn_mfma_f32_16x16x32_bf16(fah[mt], fbl[nt], acc[mt][nt], 0, 0, 0);
      }
    __syncthreads();
  }
#pragma unroll
  for (int mt = 0; mt < 4; ++mt) {
    int row = rowBase + wm*64 + mt*16 + (l >> 4)*4;
#pragma unroll
    for (int nt = 0; nt < 4; ++nt) {
      int col = colBase + wn*64 + nt*16 + (l & 15);
      float bv = (bias != nullptr) ? bias[col] : 0.f;
#pragma unroll
      for (int rg = 0; rg < 4; ++rg) {
        float v = acc[mt][nt][rg];
        if (mode == 1)      v = 0.60653066f * dsigm(v + bv);
        else if (mode == 2) v = dsigm(v + bv);
        else if (mode == 3) v = v + bv;
        C[(size_t)(row + rg)*ldc + col] = v;
      }
    }
  }
}

//==================== 4. activation between LoRA stages ====================
__global__ void k_act(const float* __restrict__ in, float* __restrict__ out, int logc, int mode)
{
  int id = blockIdx.x * 256 + threadIdx.x;
  int r = id >> logc, c = id & ((1 << logc) - 1);
  float v = in[r * 128 + c];
  if (mode == 1) v = tanhf(v);
  else if (mode == 2) v = dsigm(v);
  out[id] = v;
}

//==================== 5. scan prep: kk normalize + k update + b=kk*a ====================
__global__ void k_scanprep(float* __restrict__ kA, float* __restrict__ aA,
                           const float* __restrict__ kkw, const float* __restrict__ kaw,
                           float* __restrict__ kkA)
{
  size_t gt = (size_t)blockIdx.x * 256u + threadIdx.x;
  int d = (int)(gt & 63);
  size_t flat = gt >> 6;
  int c = (int)((flat & 15) * 64 + d);
  float k0 = kA[gt], av = aA[gt];
  float kkv = k0 * kkw[c];
  float ss = kkv * kkv;
  ss += __shfl_xor(ss, 1);  ss += __shfl_xor(ss, 2);  ss += __shfl_xor(ss, 4);
  ss += __shfl_xor(ss, 8);  ss += __shfl_xor(ss, 16); ss += __shfl_xor(ss, 32);
  float inv = 1.f / fmaxf(sqrtf(ss), 1e-12f);
  float kkn = kkv * inv;
  kkA[gt] = kkn;               // a_scan = -kkn (negation applied in-kernel)
  aA[gt]  = kkn * av;          // b_scan = kkn * a_head
  kA[gt]  = k0 * fmaf(av - 1.f, kaw[c], 1.f);
}

//==================== 6a. chunked scan pass 1 ====================
struct Step2 { float4 ew[2], kk[2], bb[2], kv[2], rr[2]; float vi; };

__device__ __forceinline__ void load_step2(Step2& d,
    const float* __restrict__ ewA, const float* __restrict__ kkA, const float* __restrict__ bbA,
    const float* __restrict__ kA, const float* __restrict__ rA, const float* __restrict__ vA,
    size_t base, int j0, int i)
{
  d.ew[0] = *(const float4*)(ewA + base + j0); d.ew[1] = *(const float4*)(ewA + base + j0 + 4);
  d.kk[0] = *(const float4*)(kkA + base + j0); d.kk[1] = *(const float4*)(kkA + base + j0 + 4);
  d.bb[0] = *(const float4*)(bbA + base + j0); d.bb[1] = *(const float4*)(bbA + base + j0 + 4);
  d.kv[0] = *(const float4*)(kA  + base + j0); d.kv[1] = *(const float4*)(kA  + base + j0 + 4);
  d.rr[0] = *(const float4*)(rA  + base + j0); d.rr[1] = *(const float4*)(rA  + base + j0 + 4);
  d.vi = vA[base + i];
}

__device__ __forceinline__ void step2_compute(const Step2& d, float* u, float* p,
    float* __restrict__ o0A, float* __restrict__ zA, size_t base, int i, int q)
{
  float uk = 0.f, pk = 0.f;
#define RED(SI, U, F) { uk += u[SI]*d.kk[U].F; pk += p[SI]*d.kk[U].F; }
  RED(0,0,x) RED(1,0,y) RED(2,0,z) RED(3,0,w)
  RED(4,1,x) RED(5,1,y) RED(6,1,z) RED(7,1,w)
#undef RED
  uk += __shfl_xor(uk, 1); uk += __shfl_xor(uk, 2); uk += __shfl_xor(uk, 4);
  pk += __shfl_xor(pk, 1); pk += __shfl_xor(pk, 2); pk += __shfl_xor(pk, 4);
  const float su = -uk, sp = -pk, vi = d.vi;
  float oo = 0.f, zz = 0.f;
#define UPD(SI, U, F) { \
    float uu = u[SI]*d.ew[U].F + su*d.bb[U].F + vi*d.kv[U].F; u[SI] = uu; oo += uu*d.rr[U].F; \
    float pp = p[SI]*d.ew[U].F + sp*d.bb[U].F;               p[SI] = pp; zz += pp*d.rr[U].F; }
  UPD(0,0,x) UPD(1,0,y) UPD(2,0,z) UPD(3,0,w)
  UPD(4,1,x) UPD(5,1,y) UPD(6,1,z) UPD(7,1,w)
#undef UPD
  oo += __shfl_xor(oo, 1); oo += __shfl_xor(oo, 2); oo += __shfl_xor(oo, 4);
  zz += __shfl_xor(zz, 1); zz += __shfl_xor(zz, 2); zz += __shfl_xor(zz, 4);
  if (q == 0) { o0A[base + i] = oo; zA[base + i] = zz; }
}

__global__ __launch_bounds__(512) void k_scan_p1(
    const float* __restrict__ rA, const float* __restrict__ ewA,
    const float* __restrict__ kA, const float* __restrict__ vA,
    const float* __restrict__ kkA, const float* __restrict__ bbA,
    float* __restrict__ o0A, float* __restrict__ zA,
    float* __restrict__ UcA, float* __restrict__ PTcA)
{
  const int blk = blockIdx.x;
  const int bh = blk & 31, c = blk >> 5;
  const int b = bh >> 4, h = bh & 15;
  const int tid = threadIdx.x;
  const int i = tid >> 3, q = tid & 7, j0 = q * 8;
  const size_t base0 = (size_t)b*2048*1024 + (size_t)h*64 + (size_t)(c*64)*1024;
  float u[8], p[8];
#pragma unroll
  for (int jj = 0; jj < 8; ++jj) { u[jj] = 0.f; p[jj] = (j0 + jj == i) ? 1.f : 0.f; }

  Step2 d0, d1;
  load_step2(d0, ewA,kkA,bbA,kA,rA,vA, base0,        j0, i);
  load_step2(d1, ewA,kkA,bbA,kA,rA,vA, base0 + 1024, j0, i);
  for (int tl = 0; tl < 64; tl += 2) {
    step2_compute(d0, u, p, o0A, zA, base0 + (size_t)tl*1024, i, q);
    if (tl + 2 < 64) load_step2(d0, ewA,kkA,bbA,kA,rA,vA, base0 + (size_t)(tl+2)*1024, j0, i);
    step2_compute(d1, u, p, o0A, zA, base0 + (size_t)(tl+1)*1024, i, q);
    if (tl + 3 < 64) load_step2(d1, ewA,kkA,bbA,kA,rA,vA, base0 + (size_t)(tl+3)*1024, j0, i);
  }

  const size_t cbase = ((size_t)(bh*32 + c)) * 4096;
  *(float4*)(UcA + cbase + (size_t)i*64 + j0)     = make_float4(u[0],u[1],u[2],u[3]);
  *(float4*)(UcA + cbase + (size_t)i*64 + j0 + 4) = make_float4(u[4],u[5],u[6],u[7]);
  __shared__ float lds[64][65];
#pragma unroll
  for (int jj = 0; jj < 8; ++jj) lds[i][j0 + jj] = p[jj];
  __syncthreads();
  float4 w0 = make_float4(lds[j0+0][i], lds[j0+1][i], lds[j0+2][i], lds[j0+3][i]);
  float4 w1 = make_float4(lds[j0+4][i], lds[j0+5][i], lds[j0+6][i], lds[j0+7][i]);
  *(float4*)(PTcA + cbase + (size_t)i*64 + j0)     = w0;
  *(float4*)(PTcA + cbase + (size_t)i*64 + j0 + 4) = w1;
}

//==================== 6b. chain: S_{c+1} = U_c + S_c @ P_c, store S0_c ====================
// 32 blocks (one per bh) x 4 waves; wave w owns cols [w*16, w*16+16).
__device__ __forceinline__ void chain_body(int c, int bh, int w, int lr, int lq,
    float (&Slds)[64][65], f32x4 (&acc)[4],
    float (&u_c)[4][4], float4 (&p_c)[2][2],
    float (&u_n)[4][4], float4 (&p_n)[2][2],
    const float* __restrict__ UcA, const float* __restrict__ PTcA,
    float* __restrict__ S0A)
{
  // 1. S_old -> LDS (+ S0A for correction kernel)
  const size_t s0base = ((size_t)bh*32 + c) * 4096;
#pragma unroll
  for (int mt = 0; mt < 4; ++mt)
#pragma unroll
    for (int rg = 0; rg < 4; ++rg) {
      Slds[mt*16 + lq*4 + rg][w*16 + lr] = acc[mt][rg];
      if (c > 0) S0A[s0base + (size_t)(mt*16 + lq*4 + rg)*64 + w*16 + lr] = acc[mt][rg];
    }
  __syncthreads();
  // 2. prefetch chunk c+1
  if (c + 1 < 32) {
    const size_t nbase = ((size_t)bh*32 + c + 1) * 4096;
#pragma unroll
    for (int mt = 0; mt < 4; ++mt)
#pragma unroll
      for (int rg = 0; rg < 4; ++rg)
        u_n[mt][rg] = UcA[nbase + (size_t)(mt*16 + lq*4 + rg)*64 + w*16 + lr];
#pragma unroll
    for (int kt = 0; kt < 2; ++kt)
#pragma unroll
      for (int hh = 0; hh < 2; ++hh)
        p_n[kt][hh] = *(const float4*)(PTcA + nbase + (size_t)(w*16 + lr)*64 + kt*32 + lq*8 + hh*4);
  }
  // 3. split PT(cur)
  short8 pbh[2], pbl[2];
#pragma unroll
  for (int kt = 0; kt < 2; ++kt) {
    float f[8] = {p_c[kt][0].x, p_c[kt][0].y, p_c[kt][0].z, p_c[kt][0].w,
                  p_c[kt][1].x, p_c[kt][1].y, p_c[kt][1].z, p_c[kt][1].w};
    split8(f, pbh[kt], pbl[kt]);
  }
  // 4. acc = U + S_old @ P
  f32x4 nacc[4];
#pragma unroll
  for (int mt = 0; mt < 4; ++mt) {
    f32x4 z = {u_c[mt][0], u_c[mt][1], u_c[mt][2], u_c[mt][3]};
    nacc[mt] = z;
  }
#pragma unroll
  for (int kt = 0; kt < 2; ++kt)
#pragma unroll
    for (int mt = 0; mt < 4; ++mt) {
      float f[8];
#pragma unroll
      for (int e = 0; e < 8; ++e) f[e] = Slds[mt*16 + lr][kt*32 + lq*8 + e];
      short8 sah, sal;
      split8(f, sah, sal);
      nacc[mt] = __builtin_amdgcn_mfma_f32_16x16x32_bf16(sah, pbh[kt], nacc[mt], 0, 0, 0);
      nacc[mt] = __builtin_amdgcn_mfma_f32_16x16x32_bf16(sal, pbh[kt], nacc[mt], 0, 0, 0);
      nacc[mt] = __builtin_amdgcn_mfma_f32_16x16x32_bf16(sah, pbl[kt], nacc[mt], 0, 0, 0);
    }
#pragma unroll
  for (int mt = 0; mt < 4; ++mt) acc[mt] = nacc[mt];
  __syncthreads();
}

__global__ __launch_bounds__(256) void k_chain(
    const float* __restrict__ UcA, const float* __restrict__ PTcA,
    float* __restrict__ S0A)
{
  const int bh = blockIdx.x;
  const int l = threadIdx.x & 63, w = threadIdx.x >> 6;
  const int lr = l & 15, lq = l >> 4;
  __shared__ float Slds[64][65];

  f32x4 acc[4];
#pragma unroll
  for (int mt = 0; mt < 4; ++mt) { f32x4 z = {0.f,0.f,0.f,0.f}; acc[mt] = z; }

  float u0[4][4], u1[4][4];
  float4 p0[2][2], p1[2][2];
  // load chunk 0
  {
    const size_t cbase = (size_t)bh * 32 * 4096;
#pragma unroll
    for (int mt = 0; mt < 4; ++mt)
#pragma unroll
      for (int rg = 0; rg < 4; ++rg)
        u0[mt][rg] = UcA[cbase + (size_t)(mt*16 + lq*4 + rg)*64 + w*16 + lr];
#pragma unroll
    for (int kt = 0; kt < 2; ++kt)
#pragma unroll
      for (int hh = 0; hh < 2; ++hh)
        p0[kt][hh] = *(const float4*)(PTcA + cbase + (size_t)(w*16 + lr)*64 + kt*32 + lq*8 + hh*4);
  }
  for (int c = 0; c < 32; c += 2) {
    chain_body(c,     bh, w, lr, lq, Slds, acc, u0, p0, u1, p1, UcA, PTcA, S0A);
    chain_body(c + 1, bh, w, lr, lq, Slds, acc, u1, p1, u0, p0, UcA, PTcA, S0A);
  }
}

//==================== 6c. correction: o[c*64+tl] += Z_c @ S0_c^T ====================
// 992 blocks = (chunk-1) * 32 + bh, 4 waves; wave w owns rows tl in [w*16, w*16+16).
__global__ __launch_bounds__(256) void k_correct(
    const float* __restrict__ S0A, const float* __restrict__ zA, float* __restrict__ oA)
{
  const int blk = blockIdx.x;
  const int bh = blk & 31;
  const int c  = (blk >> 5) + 1;          // chunks 1..31
  const int b = bh >> 4, h = bh & 15;
  const int l = threadIdx.x & 63, w = threadIdx.x >> 6;
  const int lr = l & 15, lq = l >> 4;
  const size_t s0base = ((size_t)bh*32 + c) * 4096;

  short8 sbh[4][2], sbl[4][2];
#pragma unroll
  for (int nt = 0; nt < 4; ++nt)
#pragma unroll
    for (int kt = 0; kt < 2; ++kt) {
      float f[8];
#pragma unroll
      for (int e = 0; e < 8; ++e)
        f[e] = S0A[s0base + (size_t)(nt*16 + lr)*64 + kt*32 + lq*8 + e];
      split8(f, sbh[nt][kt], sbl[nt][kt]);
    }
  short8 zh[2], zl[2];
#pragma unroll
  for (int kt = 0; kt < 2; ++kt) {
    const float* zp = zA + ((size_t)(b*2048 + c*64 + w*16 + lr)*16 + h)*64 + kt*32 + lq*8;
    float f[8];
#pragma unroll
    for (int e = 0; e < 8; ++e) f[e] = zp[e];
    split8(f, zh[kt], zl[kt]);
  }
  f32x4 a2[4];
#pragma unroll
  for (int nt = 0; nt < 4; ++nt) { f32x4 z = {0.f,0.f,0.f,0.f}; a2[nt] = z; }
#pragma unroll
  for (int kt = 0; kt < 2; ++kt)
#pragma unroll
    for (int nt = 0; nt < 4; ++nt) {
      a2[nt] = __builtin_amdgcn_mfma_f32_16x16x32_bf16(zh[kt], sbh[nt][kt], a2[nt], 0, 0, 0);
      a2[nt] = __builtin_amdgcn_mfma_f32_16x16x32_bf16(zl[kt], sbh[nt][kt], a2[nt], 0, 0, 0);
      a2[nt] = __builtin_amdgcn_mfma_f32_16x16x32_bf16(zh[kt], sbl[nt][kt], a2[nt], 0, 0, 0);
    }
#pragma unroll
  for (int nt = 0; nt < 4; ++nt)
#pragma unroll
    for (int rg = 0; rg < 4; ++rg) {
      int tl = w*16 + lq*4 + rg, ii = nt*16 + lr;
      size_t ad = ((size_t)(b*2048 + c*64 + tl)*16 + h)*64 + ii;
      oA[ad] += a2[nt][rg];
    }
}

//==================== 7. GroupNorm + bonus + gate (fp32) ====================
__global__ void k_post(const float* __restrict__ oA, const float* __restrict__ rA,
    const float* __restrict__ kA, const float* __restrict__ vA,
    const float* __restrict__ rk, const float* __restrict__ gnw, const float* __restrict__ gnb,
    const float* __restrict__ gA, float* __restrict__ yA)
{
  size_t gt = (size_t)blockIdx.x * 256u + threadIdx.x;
  int d = (int)(gt & 63);
  size_t flat = gt >> 6;
  int c = (int)((flat & 15) * 64 + d);
  float ov = oA[gt];
  float ss = ov;
  ss += __shfl_xor(ss, 1);  ss += __shfl_xor(ss, 2);  ss += __shfl_xor(ss, 4);
  ss += __shfl_xor(ss, 8);  ss += __shfl_xor(ss, 16); ss += __shfl_xor(ss, 32);
  float mean = ss * (1.f/64.f);
  float dm = ov - mean;
  float vv = dm * dm;
  vv += __shfl_xor(vv, 1);  vv += __shfl_xor(vv, 2);  vv += __shfl_xor(vv, 4);
  vv += __shfl_xor(vv, 8);  vv += __shfl_xor(vv, 16); vv += __shfl_xor(vv, 32);
  float var = vv * (1.f/64.f);
  float y = dm * rsqrtf(var + 1e-5f) * gnw[c] + gnb[c];
  float pr = rA[gt] * kA[gt] * rk[c];
  pr += __shfl_xor(pr, 1);  pr += __shfl_xor(pr, 2);  pr += __shfl_xor(pr, 4);
  pr += __shfl_xor(pr, 8);  pr += __shfl_xor(pr, 16); pr += __shfl_xor(pr, 32);
  y += pr * vA[gt];
  y *= gA[gt];
  yA[gt] = y;
}

//==================== host ====================
extern "C" void kernel_launch(void* const* d_in, const int* in_sizes, int n_in,
                              void* d_out, int out_size, void* d_ws, size_t ws_size,
                              hipStream_t stream)
{
  (void)in_sizes; (void)n_in; (void)out_size; (void)ws_size;
  const float* hs     = (const float*)d_in[0];
  const float* x_r    = (const float*)d_in[1];
  const float* x_w    = (const float*)d_in[2];
  const float* x_k    = (const float*)d_in[3];
  const float* x_v    = (const float*)d_in[4];
  const float* x_a    = (const float*)d_in[5];
  const float* k_k    = (const float*)d_in[7];
  const float* k_a    = (const float*)d_in[8];
  const float* r_k    = (const float*)d_in[9];
  const float* W_r    = (const float*)d_in[10];
  const float* W_k    = (const float*)d_in[11];
  const float* W_v    = (const float*)d_in[12];
  const float* W_o    = (const float*)d_in[13];
  const float* wla    = (const float*)d_in[14];
  const float* wlb    = (const float*)d_in[15];
  const float* wlbias = (const float*)d_in[16];
  const float* ala    = (const float*)d_in[17];
  const float* alb    = (const float*)d_in[18];
  const float* albias = (const float*)d_in[19];
  const float* gla    = (const float*)d_in[20];
  const float* glb    = (const float*)d_in[21];
  const float* glbias = (const float*)d_in[22];
  const float* gnw    = (const float*)d_in[23];
  const float* gnb    = (const float*)d_in[24];

  char* ws = (char*)d_ws;
  constexpr size_t MB = 1024u*1024u;
  size_t cur = 0;
  auto take = [&](size_t bytes) { size_t o = cur; cur += (bytes + 255) & ~(size_t)255; return o; };

  float* xr_f = (float*)(ws + take(16*MB));
  float* xw_f = (float*)(ws + take(16*MB));
  float* xk_f = (float*)(ws + take(16*MB));
  float* xv_f = (float*)(ws + take(16*MB));
  float* xa_f = (float*)(ws + take(16*MB));
  float* Wr_t  = (float*)(ws + take(4*MB));
  float* Wk_t  = (float*)(ws + take(4*MB));
  float* Wv_t  = (float*)(ws + take(4*MB));
  float* Wo_t  = (float*)(ws + take(4*MB));
  float* wla_t = (float*)(ws + take(128*1024*4));
  float* wlb_t = (float*)(ws + take(1024*64*4));
  float* ala_t = (float*)(ws + take(128*1024*4));
  float* alb_t = (float*)(ws + take(1024*64*4));
  float* gla_t = (float*)(ws + take(128*1024*4));
  float* glb_t = (float*)(ws + take(1024*128*4));
  float* r_f  = (float*)(ws + take(16*MB));
  float* k_f  = (float*)(ws + take(16*MB));
  float* v_f  = (float*)(ws + take(16*MB));
  float* t1   = (float*)(ws + take(2*MB));
  float* t2   = (float*)(ws + take(2*MB));
  float* z_f  = (float*)(ws + take(16*MB));      // z_t = P_t r_t, layout (b,t,h,m)
  float* Uc_f = (float*)(ws + take(16*MB));      // [bh][32][64][64]
  float* PT_f = (float*)(ws + take(16*MB));      // [bh][32][64][64] (P^T)
  // aliases (lifetime-checked against launch order):
  float* ew_f = xr_f;   // xr consumed by r-GEMM before ew written
  float* a_f  = xk_f;   // xk consumed by k-GEMM; holds a then b=kk*a
  float* kk_f = xw_f;   // xw consumed by w-LoRA stage1; kk dead after scan_p1
  float* g_f  = xv_f;   // xv consumed by v-GEMM
  float* y_f  = xa_f;   // xa consumed by a-LoRA stage1
  float* S0_f = xw_f;   // reuse kk_f storage: kk dead once k_chain runs
  float* oF   = (float*)d_out;

  // 1. prep
  k_prep<<<16384, 256, 0, stream>>>(hs, x_r, x_w, x_k, x_v, x_a,
                                    xr_f, xw_f, xk_f, xv_f, xa_f);
  // 2. weight transposes
  SrcP sp; DstP dp;
  sp.p[0]=W_r; sp.p[1]=W_k; sp.p[2]=W_v; sp.p[3]=W_o;
  sp.p[4]=wla; sp.p[5]=wlb; sp.p[6]=ala; sp.p[7]=alb; sp.p[8]=gla; sp.p[9]=glb;
  dp.p[0]=Wr_t; dp.p[1]=Wk_t; dp.p[2]=Wv_t; dp.p[3]=Wo_t;
  dp.p[4]=wla_t; dp.p[5]=wlb_t; dp.p[6]=ala_t; dp.p[7]=alb_t; dp.p[8]=gla_t; dp.p[9]=glb_t;
  k_transpose<<<dim3(32,32,10), dim3(32,8), 0, stream>>>(sp, dp);

  // 3. big projections
  k_gemm_split<<<dim3(32,8), 256, 0, stream>>>(xr_f,1024, Wr_t,1024, r_f,1024, nullptr, 0, 1024);
  k_gemm_split<<<dim3(32,8), 256, 0, stream>>>(xk_f,1024, Wk_t,1024, k_f,1024, nullptr, 0, 1024);
  k_gemm_split<<<dim3(32,8), 256, 0, stream>>>(xv_f,1024, Wv_t,1024, v_f,1024, nullptr, 0, 1024);

  // 4. w-LoRA
  k_gemm_split<<<dim3(32,1), 256, 0, stream>>>(xw_f,1024, wla_t,1024, t1,128, nullptr, 0, 1024);
  k_act<<<1024, 256, 0, stream>>>(t1, t2, 6, 1);
  k_gemm_split<<<dim3(32,8), 256, 0, stream>>>(t2,64, wlb_t,64, ew_f,1024, wlbias, 1, 64);

  // 5. a-LoRA
  k_gemm_split<<<dim3(32,1), 256, 0, stream>>>(xa_f,1024, ala_t,1024, t1,128, nullptr, 0, 1024);
  k_act<<<1024, 256, 0, stream>>>(t1, t2, 6, 0);
  k_gemm_split<<<dim3(32,8), 256, 0, stream>>>(t2,64, alb_t,64, a_f,1024, albias, 2, 64);

  // 6. g-LoRA
  k_gemm_split<<<dim3(32,1), 256, 0, stream>>>(r_f,1024, gla_t,1024, t1,128, nullptr, 0, 1024);
  k_act<<<2048, 256, 0, stream>>>(t1, t2, 7, 2);
  k_gemm_split<<<dim3(32,8), 256, 0, stream>>>(t2,128, glb_t,128, g_f,1024, glbias, 3, 128);

  // 7. kk normalize + k update + b precompute
  k_scanprep<<<16384, 256, 0, stream>>>(k_f, a_f, k_k, k_a, kk_f);

  // 8. chunked scan
  k_scan_p1<<<1024, 512, 0, stream>>>(r_f, ew_f, k_f, v_f, kk_f, a_f, oF, z_f, Uc_f, PT_f);
  k_chain<<<32, 256, 0, stream>>>(Uc_f, PT_f, S0_f);
  k_correct<<<992, 256, 0, stream>>>(S0_f, z_f, oF);

  // 9. groupnorm + bonus + gate
  k_post<<<16384, 256, 0, stream>>>(oF, r_f, k_f, v_f, r_k, gnw, gnb, g_f, y_f);

  // 10. output projection (overwrites d_out)
  k_gemm_split<<<dim3(32,8), 256, 0, stream>>>(y_f,1024, Wo_t,1024, (float*)d_out,1024, nullptr, 0, 1024);
}

// Round 5
// 648.182 us; speedup vs baseline: 2.5678x; 1.0931x over previous
//
#include <hip/hip_runtime.h>
#include <hip/hip_bf16.h>
#include <stdint.h>
#include <stddef.h>

typedef __hip_bfloat16 bf16;
typedef __attribute__((ext_vector_type(8))) short short8;
typedef __attribute__((ext_vector_type(4))) float f32x4;

__device__ __forceinline__ float dsigm(float z){ return 1.f/(1.f+expf(-z)); }

// split fp32 -> hi (bit-truncated bf16) + lo (rounded bf16 residual); hi+lo ~ 16 mantissa bits
__device__ __forceinline__ void split1(float v, unsigned short& h, unsigned short& l) {
  unsigned int u = __builtin_bit_cast(unsigned int, v);
  h = (unsigned short)(u >> 16);
  float hf = __builtin_bit_cast(float, u & 0xFFFF0000u);
  bf16 lb = __float2bfloat16(v - hf);
  l = __builtin_bit_cast(unsigned short, lb);
}

__device__ __forceinline__ void split8(const float* f, short8& h, short8& l) {
#pragma unroll
  for (int e = 0; e < 8; ++e) {
    unsigned short hh, ll;
    split1(f[e], hh, ll);
    h[e] = (short)hh; l[e] = (short)ll;
  }
}

//==================== 1. time-shift lerp -> fp32 operands ====================
__global__ void k_prep(const float* __restrict__ hs,
    const float* __restrict__ mr, const float* __restrict__ mw, const float* __restrict__ mk,
    const float* __restrict__ mv, const float* __restrict__ ma,
    float* __restrict__ oxr, float* __restrict__ oxw, float* __restrict__ oxk,
    float* __restrict__ oxv, float* __restrict__ oxa)
{
  size_t id = (size_t)blockIdx.x*256u + threadIdx.x;
  if (id >= (size_t)4194304) return;
  int c = (int)(id & 1023);
  int t = (int)((id >> 10) & 2047);
  float cur = hs[id];
  float prev = (t > 0) ? hs[id - 1024] : 0.f;
  float d = prev - cur;
  oxr[id] = fmaf(d, mr[c], cur);
  oxw[id] = fmaf(d, mw[c], cur);
  oxk[id] = fmaf(d, mk[c], cur);
  oxv[id] = fmaf(d, mv[c], cur);
  oxa[id] = fmaf(d, ma[c], cur);
}

//==================== 2. weight transpose (fp32) ====================
struct SrcP { const float* p[10]; };
struct DstP { float* p[10]; };

__global__ void k_transpose(SrcP S, DstP Dd)
{
  static constexpr int TR[10]  = {1024,1024,1024,1024,1024,  64,1024,  64,1024, 128};
  static constexpr int TCC[10] = {1024,1024,1024,1024,  64,1024,  64,1024, 128,1024};
  static constexpr int TCP[10] = {1024,1024,1024,1024, 128,1024, 128,1024, 128,1024};
  int z = blockIdx.z;
  int R = TR[z], Cc = TCC[z], Cp = TCP[z];
  int n0 = blockIdx.x * 32, r0 = blockIdx.y * 32;
  if (n0 >= Cp || r0 >= R) return;
  const float* src = S.p[z];
  float* dst = Dd.p[z];
  int tx = threadIdx.x, ty = threadIdx.y;
  __shared__ float tile[32][33];
  if (n0 < Cc) {
#pragma unroll
    for (int i = 0; i < 4; ++i)
      tile[ty + 8*i][tx] = src[(size_t)(r0 + ty + 8*i)*Cc + n0 + tx];
    __syncthreads();
#pragma unroll
    for (int i = 0; i < 4; ++i)
      dst[(size_t)(n0 + ty + 8*i)*R + r0 + tx] = tile[tx][ty + 8*i];
  } else {
#pragma unroll
    for (int i = 0; i < 4; ++i)
      dst[(size_t)(n0 + ty + 8*i)*R + r0 + tx] = 0.f;
  }
}

//==================== 3. split-bf16 MFMA GEMM (fp32-accurate) ====================
// C[M][N] = A[M][K] (fp32) * Bt[N][K]^T (fp32). tile 128x128, BK=32, 4 waves.
// mode: 0 none | 1 ew=e^-0.5*sigmoid(x+bias) | 2 sigmoid(x+bias) | 3 x+bias
__global__ __launch_bounds__(256) void k_gemm_split(
    const float* __restrict__ A, int lda,
    const float* __restrict__ Bt, int ldb,
    float* __restrict__ C, int ldc,
    const float* __restrict__ bias, int mode, int K)
{
  __shared__ __align__(16) unsigned short AsH[128*32];
  __shared__ __align__(16) unsigned short AsL[128*32];
  __shared__ __align__(16) unsigned short BsH[128*32];
  __shared__ __align__(16) unsigned short BsL[128*32];
  const int tid = threadIdx.x;
  const int l = tid & 63, w = tid >> 6;
  const int wm = w >> 1, wn = w & 1;
  const int rowBase = blockIdx.x * 128, colBase = blockIdx.y * 128;
  const int lrow = l & 15, kid = (l >> 4) * 8;

  f32x4 acc[4][4];
#pragma unroll
  for (int i = 0; i < 4; ++i)
#pragma unroll
    for (int j = 0; j < 4; ++j) { f32x4 z = {0.f,0.f,0.f,0.f}; acc[i][j] = z; }

  const int nk = K >> 5;
  for (int kt = 0; kt < nk; ++kt) {
#pragma unroll
    for (int rr = 0; rr < 4; ++rr) {
      int idx = rr*256 + tid;
      int ar = idx >> 3, ac = (idx & 7) * 4;
      float4 va = *(const float4*)(A  + (size_t)(rowBase + ar)*lda + kt*32 + ac);
      float4 vb = *(const float4*)(Bt + (size_t)(colBase + ar)*ldb + kt*32 + ac);
      ushort4 ha, la, hb, lb;
      split1(va.x, ha.x, la.x); split1(va.y, ha.y, la.y);
      split1(va.z, ha.z, la.z); split1(va.w, ha.w, la.w);
      split1(vb.x, hb.x, lb.x); split1(vb.y, hb.y, lb.y);
      split1(vb.z, hb.z, lb.z); split1(vb.w, hb.w, lb.w);
      *(ushort4*)&AsH[ar*32 + ac] = ha;
      *(ushort4*)&AsL[ar*32 + ac] = la;
      *(ushort4*)&BsH[ar*32 + ac] = hb;
      *(ushort4*)&BsL[ar*32 + ac] = lb;
    }
    __syncthreads();
    short8 fah[4], fal[4], fbh[4], fbl[4];
#pragma unroll
    for (int mt = 0; mt < 4; ++mt) {
      int ro = (wm*64 + mt*16 + lrow)*32 + kid;
      fah[mt] = *(const short8*)&AsH[ro];
      fal[mt] = *(const short8*)&AsL[ro];
    }
#pragma unroll
    for (int nt = 0; nt < 4; ++nt) {
      int ro = (wn*64 + nt*16 + lrow)*32 + kid;
      fbh[nt] = *(const short8*)&BsH[ro];
      fbl[nt] = *(const short8*)&BsL[ro];
    }
#pragma unroll
    for (int mt = 0; mt < 4; ++mt)
#pragma unroll
      for (int nt = 0; nt < 4; ++nt) {
        acc[mt][nt] = __builtin_amdgcn_mfma_f32_16x16x32_bf16(fah[mt], fbh[nt], acc[mt][nt], 0, 0, 0);
        acc[mt][nt] = __builtin_amdgcn_mfma_f32_16x16x32_bf16(fal[mt], fbh[nt], acc[mt][nt], 0, 0, 0);
        acc[mt][nt] = __builtin_amdgcn_mfma_f32_16x16x32_bf16(fah[mt], fbl[nt], acc[mt][nt], 0, 0, 0);
      }
    __syncthreads();
  }
#pragma unroll
  for (int mt = 0; mt < 4; ++mt) {
    int row = rowBase + wm*64 + mt*16 + (l >> 4)*4;
#pragma unroll
    for (int nt = 0; nt < 4; ++nt) {
      int col = colBase + wn*64 + nt*16 + (l & 15);
      float bv = (bias != nullptr) ? bias[col] : 0.f;
#pragma unroll
      for (int rg = 0; rg < 4; ++rg) {
        float v = acc[mt][nt][rg];
        if (mode == 1)      v = 0.60653066f * dsigm(v + bv);
        else if (mode == 2) v = dsigm(v + bv);
        else if (mode == 3) v = v + bv;
        C[(size_t)(row + rg)*ldc + col] = v;
      }
    }
  }
}

//==================== 4. activation between LoRA stages ====================
__global__ void k_act(const float* __restrict__ in, float* __restrict__ out, int logc, int mode)
{
  int id = blockIdx.x * 256 + threadIdx.x;
  int r = id >> logc, c = id & ((1 << logc) - 1);
  float v = in[r * 128 + c];
  if (mode == 1) v = tanhf(v);
  else if (mode == 2) v = dsigm(v);
  out[id] = v;
}

//==================== 5. scan prep: kk normalize + k update + b=kk*a ====================
__global__ void k_scanprep(float* __restrict__ kA, float* __restrict__ aA,
                           const float* __restrict__ kkw, const float* __restrict__ kaw,
                           float* __restrict__ kkA)
{
  size_t gt = (size_t)blockIdx.x * 256u + threadIdx.x;
  int d = (int)(gt & 63);
  size_t flat = gt >> 6;
  int c = (int)((flat & 15) * 64 + d);
  float k0 = kA[gt], av = aA[gt];
  float kkv = k0 * kkw[c];
  float ss = kkv * kkv;
  ss += __shfl_xor(ss, 1);  ss += __shfl_xor(ss, 2);  ss += __shfl_xor(ss, 4);
  ss += __shfl_xor(ss, 8);  ss += __shfl_xor(ss, 16); ss += __shfl_xor(ss, 32);
  float inv = 1.f / fmaxf(sqrtf(ss), 1e-12f);
  float kkn = kkv * inv;
  kkA[gt] = kkn;               // a_scan = -kkn (negation applied in-kernel)
  aA[gt]  = kkn * av;          // b_scan = kkn * a_head
  kA[gt]  = k0 * fmaf(av - 1.f, kaw[c], 1.f);
}

//==================== 6a. chunked scan pass 1 (LDS-staged) ====================
// Per (bh, chunk): run recurrence from U=0 and P=I over L=64 steps.
// Step vectors staged through LDS in 8-step groups (double-buffered):
// per-step payload is only 6x64 floats/block; direct global loads would be
// 64x redundant across the i-dimension (L1-BW bound, measured round 4).
// LDS layout (floats): [buf:2][array:6][step:8][elem:64]; arrays:
//   0=ew 1=kk 2=bb 3=k 4=r 5=v
#define SP1_EW 0
#define SP1_KK 512
#define SP1_BB 1024
#define SP1_KV 1536
#define SP1_RR 2048
#define SP1_VV 2560

__device__ __forceinline__ void step_lds(const float* __restrict__ sb, int s,
    float* u, float* p, float* __restrict__ o0A, float* __restrict__ zA,
    size_t base, int i, int q, int j0)
{
  float4 ew0 = *(const float4*)(sb + SP1_EW + s*64 + j0);
  float4 ew1 = *(const float4*)(sb + SP1_EW + s*64 + j0 + 4);
  float4 kk0 = *(const float4*)(sb + SP1_KK + s*64 + j0);
  float4 kk1 = *(const float4*)(sb + SP1_KK + s*64 + j0 + 4);
  float4 bb0 = *(const float4*)(sb + SP1_BB + s*64 + j0);
  float4 bb1 = *(const float4*)(sb + SP1_BB + s*64 + j0 + 4);
  float4 kv0 = *(const float4*)(sb + SP1_KV + s*64 + j0);
  float4 kv1 = *(const float4*)(sb + SP1_KV + s*64 + j0 + 4);
  float4 rr0 = *(const float4*)(sb + SP1_RR + s*64 + j0);
  float4 rr1 = *(const float4*)(sb + SP1_RR + s*64 + j0 + 4);
  float vi = sb[SP1_VV + s*64 + i];

  float uk = 0.f, pk = 0.f;
#define RED(SI, V, F) { uk += u[SI]*V.F; pk += p[SI]*V.F; }
  RED(0,kk0,x) RED(1,kk0,y) RED(2,kk0,z) RED(3,kk0,w)
  RED(4,kk1,x) RED(5,kk1,y) RED(6,kk1,z) RED(7,kk1,w)
#undef RED
  uk += __shfl_xor(uk, 1); uk += __shfl_xor(uk, 2); uk += __shfl_xor(uk, 4);
  pk += __shfl_xor(pk, 1); pk += __shfl_xor(pk, 2); pk += __shfl_xor(pk, 4);
  const float su = -uk, sp = -pk;
  float oo = 0.f, zz = 0.f;
#define UPD(SI, E, Kv, Bv, Rv, F) { \
    float uu = u[SI]*E.F + su*Bv.F + vi*Kv.F; u[SI] = uu; oo += uu*Rv.F; \
    float pp = p[SI]*E.F + sp*Bv.F;           p[SI] = pp; zz += pp*Rv.F; }
  UPD(0,ew0,kv0,bb0,rr0,x) UPD(1,ew0,kv0,bb0,rr0,y) UPD(2,ew0,kv0,bb0,rr0,z) UPD(3,ew0,kv0,bb0,rr0,w)
  UPD(4,ew1,kv1,bb1,rr1,x) UPD(5,ew1,kv1,bb1,rr1,y) UPD(6,ew1,kv1,bb1,rr1,z) UPD(7,ew1,kv1,bb1,rr1,w)
#undef UPD
  oo += __shfl_xor(oo, 1); oo += __shfl_xor(oo, 2); oo += __shfl_xor(oo, 4);
  zz += __shfl_xor(zz, 1); zz += __shfl_xor(zz, 2); zz += __shfl_xor(zz, 4);
  if (q == 0) { o0A[base + i] = oo; zA[base + i] = zz; }
}

__global__ __launch_bounds__(512) void k_scan_p1(
    const float* __restrict__ rA, const float* __restrict__ ewA,
    const float* __restrict__ kA, const float* __restrict__ vA,
    const float* __restrict__ kkA, const float* __restrict__ bbA,
    float* __restrict__ o0A, float* __restrict__ zA,
    float* __restrict__ UcA, float* __restrict__ PTcA)
{
  const int blk = blockIdx.x;
  const int bh = blk & 31, c = blk >> 5;
  const int b = bh >> 4, h = bh & 15;
  const int tid = threadIdx.x;
  const int i = tid >> 3, q = tid & 7, j0 = q * 8;
  const size_t base0 = (size_t)b*2048*1024 + (size_t)h*64 + (size_t)(c*64)*1024;

  __shared__ __align__(16) float smem[2*3072];   // 24 KB (reused for transpose at end)

  // precompute this thread's staging slots (g-independent)
  const int a0 = tid >> 7, rm0 = tid & 127, s0 = rm0 >> 4, f40 = rm0 & 15;
  const float* pa0 = (a0 == 0) ? ewA : (a0 == 1) ? kkA : (a0 == 2) ? bbA : kA;
  const float* src0 = pa0 + base0 + (size_t)s0*1024 + f40*4;
  const int dst0 = a0*512 + s0*64 + f40*4;
  const int have2 = (tid < 256);
  const int a1 = ((tid + 512) >> 7);                 // 4 or 5 when have2
  const int rm1 = (tid + 512) & 127, s1 = rm1 >> 4, f41 = rm1 & 15;
  const float* pa1 = (a1 == 4) ? rA : vA;
  const float* src1 = pa1 + base0 + (size_t)s1*1024 + f41*4;
  const int dst1 = a1*512 + s1*64 + f41*4;

  float u[8], p[8];
#pragma unroll
  for (int jj = 0; jj < 8; ++jj) { u[jj] = 0.f; p[jj] = (j0 + jj == i) ? 1.f : 0.f; }

  // prologue: stage group 0 into buf 0
  {
    float4 n0 = *(const float4*)(src0);
    float4 n1;
    if (have2) n1 = *(const float4*)(src1);
    *(float4*)&smem[dst0] = n0;
    if (have2) *(float4*)&smem[dst1] = n1;
  }
  __syncthreads();

  int curb = 0;
  for (int g = 0; g < 8; ++g) {
    float4 n0, n1;
    if (g < 7) {
      n0 = *(const float4*)(src0 + (size_t)(g+1)*8192);
      if (have2) n1 = *(const float4*)(src1 + (size_t)(g+1)*8192);
    }
    const float* sb = smem + curb*3072;
#pragma unroll
    for (int s = 0; s < 8; ++s)
      step_lds(sb, s, u, p, o0A, zA, base0 + (size_t)(g*8 + s)*1024, i, q, j0);
    if (g < 7) {
      int nb = curb ^ 1;
      *(float4*)&smem[nb*3072 + dst0] = n0;
      if (have2) *(float4*)&smem[nb*3072 + dst1] = n1;
    }
    __syncthreads();
    curb ^= 1;
  }

  // store U_c (row-major [i][j]) and P_c^T (row-major [j][m]) for pass 2
  const size_t cbase = ((size_t)(bh*32 + c)) * 4096;
  *(float4*)(UcA + cbase + (size_t)i*64 + j0)     = make_float4(u[0],u[1],u[2],u[3]);
  *(float4*)(UcA + cbase + (size_t)i*64 + j0 + 4) = make_float4(u[4],u[5],u[6],u[7]);
  float (*lds)[65] = (float(*)[65])smem;          // 64*65*4 = 16.6 KB < 24 KB
#pragma unroll
  for (int jj = 0; jj < 8; ++jj) lds[i][j0 + jj] = p[jj];
  __syncthreads();
  float4 w0 = make_float4(lds[j0+0][i], lds[j0+1][i], lds[j0+2][i], lds[j0+3][i]);
  float4 w1 = make_float4(lds[j0+4][i], lds[j0+5][i], lds[j0+6][i], lds[j0+7][i]);
  *(float4*)(PTcA + cbase + (size_t)i*64 + j0)     = w0;
  *(float4*)(PTcA + cbase + (size_t)i*64 + j0 + 4) = w1;
}

//==================== 6b. chain: S_{c+1} = U_c + S_c @ P_c, store S0_c ====================
// 32 blocks (one per bh) x 4 waves; wave w owns cols [w*16, w*16+16).
__device__ __forceinline__ void chain_body(int c, int bh, int w, int lr, int lq,
    float (&Slds)[64][65], f32x4 (&acc)[4],
    float (&u_c)[4][4], float4 (&p_c)[2][2],
    float (&u_n)[4][4], float4 (&p_n)[2][2],
    const float* __restrict__ UcA, const float* __restrict__ PTcA,
    float* __restrict__ S0A)
{
  // 1. S_old -> LDS (+ S0A for correction kernel)
  const size_t s0base = ((size_t)bh*32 + c) * 4096;
#pragma unroll
  for (int mt = 0; mt < 4; ++mt)
#pragma unroll
    for (int rg = 0; rg < 4; ++rg) {
      Slds[mt*16 + lq*4 + rg][w*16 + lr] = acc[mt][rg];
      if (c > 0) S0A[s0base + (size_t)(mt*16 + lq*4 + rg)*64 + w*16 + lr] = acc[mt][rg];
    }
  __syncthreads();
  // 2. prefetch chunk c+1
  if (c + 1 < 32) {
    const size_t nbase = ((size_t)bh*32 + c + 1) * 4096;
#pragma unroll
    for (int mt = 0; mt < 4; ++mt)
#pragma unroll
      for (int rg = 0; rg < 4; ++rg)
        u_n[mt][rg] = UcA[nbase + (size_t)(mt*16 + lq*4 + rg)*64 + w*16 + lr];
#pragma unroll
    for (int kt = 0; kt < 2; ++kt)
#pragma unroll
      for (int hh = 0; hh < 2; ++hh)
        p_n[kt][hh] = *(const float4*)(PTcA + nbase + (size_t)(w*16 + lr)*64 + kt*32 + lq*8 + hh*4);
  }
  // 3. split PT(cur)
  short8 pbh[2], pbl[2];
#pragma unroll
  for (int kt = 0; kt < 2; ++kt) {
    float f[8] = {p_c[kt][0].x, p_c[kt][0].y, p_c[kt][0].z, p_c[kt][0].w,
                  p_c[kt][1].x, p_c[kt][1].y, p_c[kt][1].z, p_c[kt][1].w};
    split8(f, pbh[kt], pbl[kt]);
  }
  // 4. acc = U + S_old @ P
  f32x4 nacc[4];
#pragma unroll
  for (int mt = 0; mt < 4; ++mt) {
    f32x4 z = {u_c[mt][0], u_c[mt][1], u_c[mt][2], u_c[mt][3]};
    nacc[mt] = z;
  }
#pragma unroll
  for (int kt = 0; kt < 2; ++kt)
#pragma unroll
    for (int mt = 0; mt < 4; ++mt) {
      float f[8];
#pragma unroll
      for (int e = 0; e < 8; ++e) f[e] = Slds[mt*16 + lr][kt*32 + lq*8 + e];
      short8 sah, sal;
      split8(f, sah, sal);
      nacc[mt] = __builtin_amdgcn_mfma_f32_16x16x32_bf16(sah, pbh[kt], nacc[mt], 0, 0, 0);
      nacc[mt] = __builtin_amdgcn_mfma_f32_16x16x32_bf16(sal, pbh[kt], nacc[mt], 0, 0, 0);
      nacc[mt] = __builtin_amdgcn_mfma_f32_16x16x32_bf16(sah, pbl[kt], nacc[mt], 0, 0, 0);
    }
#pragma unroll
  for (int mt = 0; mt < 4; ++mt) acc[mt] = nacc[mt];
  __syncthreads();
}

__global__ __launch_bounds__(256) void k_chain(
    const float* __restrict__ UcA, const float* __restrict__ PTcA,
    float* __restrict__ S0A)
{
  const int bh = blockIdx.x;
  const int l = threadIdx.x & 63, w = threadIdx.x >> 6;
  const int lr = l & 15, lq = l >> 4;
  __shared__ float Slds[64][65];

  f32x4 acc[4];
#pragma unroll
  for (int mt = 0; mt < 4; ++mt) { f32x4 z = {0.f,0.f,0.f,0.f}; acc[mt] = z; }

  float u0[4][4], u1[4][4];
  float4 p0[2][2], p1[2][2];
  // load chunk 0
  {
    const size_t cbase = (size_t)bh * 32 * 4096;
#pragma unroll
    for (int mt = 0; mt < 4; ++mt)
#pragma unroll
      for (int rg = 0; rg < 4; ++rg)
        u0[mt][rg] = UcA[cbase + (size_t)(mt*16 + lq*4 + rg)*64 + w*16 + lr];
#pragma unroll
    for (int kt = 0; kt < 2; ++kt)
#pragma unroll
      for (int hh = 0; hh < 2; ++hh)
        p0[kt][hh] = *(const float4*)(PTcA + cbase + (size_t)(w*16 + lr)*64 + kt*32 + lq*8 + hh*4);
  }
  for (int c = 0; c < 32; c += 2) {
    chain_body(c,     bh, w, lr, lq, Slds, acc, u0, p0, u1, p1, UcA, PTcA, S0A);
    chain_body(c + 1, bh, w, lr, lq, Slds, acc, u1, p1, u0, p0, UcA, PTcA, S0A);
  }
}

//==================== 6c. correction: o[c*64+tl] += Z_c @ S0_c^T ====================
// 992 blocks = (chunk-1) * 32 + bh, 4 waves; wave w owns rows tl in [w*16, w*16+16).
__global__ __launch_bounds__(256) void k_correct(
    const float* __restrict__ S0A, const float* __restrict__ zA, float* __restrict__ oA)
{
  const int blk = blockIdx.x;
  const int bh = blk & 31;
  const int c  = (blk >> 5) + 1;          // chunks 1..31
  const int b = bh >> 4, h = bh & 15;
  const int l = threadIdx.x & 63, w = threadIdx.x >> 6;
  const int lr = l & 15, lq = l >> 4;
  const size_t s0base = ((size_t)bh*32 + c) * 4096;

  short8 sbh[4][2], sbl[4][2];
#pragma unroll
  for (int nt = 0; nt < 4; ++nt)
#pragma unroll
    for (int kt = 0; kt < 2; ++kt) {
      float f[8];
#pragma unroll
      for (int e = 0; e < 8; ++e)
        f[e] = S0A[s0base + (size_t)(nt*16 + lr)*64 + kt*32 + lq*8 + e];
      split8(f, sbh[nt][kt], sbl[nt][kt]);
    }
  short8 zh[2], zl[2];
#pragma unroll
  for (int kt = 0; kt < 2; ++kt) {
    const float* zp = zA + ((size_t)(b*2048 + c*64 + w*16 + lr)*16 + h)*64 + kt*32 + lq*8;
    float f[8];
#pragma unroll
    for (int e = 0; e < 8; ++e) f[e] = zp[e];
    split8(f, zh[kt], zl[kt]);
  }
  f32x4 a2[4];
#pragma unroll
  for (int nt = 0; nt < 4; ++nt) { f32x4 z = {0.f,0.f,0.f,0.f}; a2[nt] = z; }
#pragma unroll
  for (int kt = 0; kt < 2; ++kt)
#pragma unroll
    for (int nt = 0; nt < 4; ++nt) {
      a2[nt] = __builtin_amdgcn_mfma_f32_16x16x32_bf16(zh[kt], sbh[nt][kt], a2[nt], 0, 0, 0);
      a2[nt] = __builtin_amdgcn_mfma_f32_16x16x32_bf16(zl[kt], sbh[nt][kt], a2[nt], 0, 0, 0);
      a2[nt] = __builtin_amdgcn_mfma_f32_16x16x32_bf16(zh[kt], sbl[nt][kt], a2[nt], 0, 0, 0);
    }
#pragma unroll
  for (int nt = 0; nt < 4; ++nt)
#pragma unroll
    for (int rg = 0; rg < 4; ++rg) {
      int tl = w*16 + lq*4 + rg, ii = nt*16 + lr;
      size_t ad = ((size_t)(b*2048 + c*64 + tl)*16 + h)*64 + ii;
      oA[ad] += a2[nt][rg];
    }
}

//==================== 7. GroupNorm + bonus + gate (fp32) ====================
__global__ void k_post(const float* __restrict__ oA, const float* __restrict__ rA,
    const float* __restrict__ kA, const float* __restrict__ vA,
    const float* __restrict__ rk, const float* __restrict__ gnw, const float* __restrict__ gnb,
    const float* __restrict__ gA, float* __restrict__ yA)
{
  size_t gt = (size_t)blockIdx.x * 256u + threadIdx.x;
  int d = (int)(gt & 63);
  size_t flat = gt >> 6;
  int c = (int)((flat & 15) * 64 + d);
  float ov = oA[gt];
  float ss = ov;
  ss += __shfl_xor(ss, 1);  ss += __shfl_xor(ss, 2);  ss += __shfl_xor(ss, 4);
  ss += __shfl_xor(ss, 8);  ss += __shfl_xor(ss, 16); ss += __shfl_xor(ss, 32);
  float mean = ss * (1.f/64.f);
  float dm = ov - mean;
  float vv = dm * dm;
  vv += __shfl_xor(vv, 1);  vv += __shfl_xor(vv, 2);  vv += __shfl_xor(vv, 4);
  vv += __shfl_xor(vv, 8);  vv += __shfl_xor(vv, 16); vv += __shfl_xor(vv, 32);
  float var = vv * (1.f/64.f);
  float y = dm * rsqrtf(var + 1e-5f) * gnw[c] + gnb[c];
  float pr = rA[gt] * kA[gt] * rk[c];
  pr += __shfl_xor(pr, 1);  pr += __shfl_xor(pr, 2);  pr += __shfl_xor(pr, 4);
  pr += __shfl_xor(pr, 8);  pr += __shfl_xor(pr, 16); pr += __shfl_xor(pr, 32);
  y += pr * vA[gt];
  y *= gA[gt];
  yA[gt] = y;
}

//==================== host ====================
extern "C" void kernel_launch(void* const* d_in, const int* in_sizes, int n_in,
                              void* d_out, int out_size, void* d_ws, size_t ws_size,
                              hipStream_t stream)
{
  (void)in_sizes; (void)n_in; (void)out_size; (void)ws_size;
  const float* hs     = (const float*)d_in[0];
  const float* x_r    = (const float*)d_in[1];
  const float* x_w    = (const float*)d_in[2];
  const float* x_k    = (const float*)d_in[3];
  const float* x_v    = (const float*)d_in[4];
  const float* x_a    = (const float*)d_in[5];
  const float* k_k    = (const float*)d_in[7];
  const float* k_a    = (const float*)d_in[8];
  const float* r_k    = (const float*)d_in[9];
  const float* W_r    = (const float*)d_in[10];
  const float* W_k    = (const float*)d_in[11];
  const float* W_v    = (const float*)d_in[12];
  const float* W_o    = (const float*)d_in[13];
  const float* wla    = (const float*)d_in[14];
  const float* wlb    = (const float*)d_in[15];
  const float* wlbias = (const float*)d_in[16];
  const float* ala    = (const float*)d_in[17];
  const float* alb    = (const float*)d_in[18];
  const float* albias = (const float*)d_in[19];
  const float* gla    = (const float*)d_in[20];
  const float* glb    = (const float*)d_in[21];
  const float* glbias = (const float*)d_in[22];
  const float* gnw    = (const float*)d_in[23];
  const float* gnb    = (const float*)d_in[24];

  char* ws = (char*)d_ws;
  constexpr size_t MB = 1024u*1024u;
  size_t cur = 0;
  auto take = [&](size_t bytes) { size_t o = cur; cur += (bytes + 255) & ~(size_t)255; return o; };

  float* xr_f = (float*)(ws + take(16*MB));
  float* xw_f = (float*)(ws + take(16*MB));
  float* xk_f = (float*)(ws + take(16*MB));
  float* xv_f = (float*)(ws + take(16*MB));
  float* xa_f = (float*)(ws + take(16*MB));
  float* Wr_t  = (float*)(ws + take(4*MB));
  float* Wk_t  = (float*)(ws + take(4*MB));
  float* Wv_t  = (float*)(ws + take(4*MB));
  float* Wo_t  = (float*)(ws + take(4*MB));
  float* wla_t = (float*)(ws + take(128*1024*4));
  float* wlb_t = (float*)(ws + take(1024*64*4));
  float* ala_t = (float*)(ws + take(128*1024*4));
  float* alb_t = (float*)(ws + take(1024*64*4));
  float* gla_t = (float*)(ws + take(128*1024*4));
  float* glb_t = (float*)(ws + take(1024*128*4));
  float* r_f  = (float*)(ws + take(16*MB));
  float* k_f  = (float*)(ws + take(16*MB));
  float* v_f  = (float*)(ws + take(16*MB));
  float* t1   = (float*)(ws + take(2*MB));
  float* t2   = (float*)(ws + take(2*MB));
  float* z_f  = (float*)(ws + take(16*MB));      // z_t = P_t r_t, layout (b,t,h,m)
  float* Uc_f = (float*)(ws + take(16*MB));      // [bh][32][64][64]
  float* PT_f = (float*)(ws + take(16*MB));      // [bh][32][64][64] (P^T)
  // aliases (lifetime-checked against launch order):
  float* ew_f = xr_f;   // xr consumed by r-GEMM before ew written
  float* a_f  = xk_f;   // xk consumed by k-GEMM; holds a then b=kk*a
  float* kk_f = xw_f;   // xw consumed by w-LoRA stage1; kk dead after scan_p1
  float* g_f  = xv_f;   // xv consumed by v-GEMM
  float* y_f  = xa_f;   // xa consumed by a-LoRA stage1
  float* S0_f = xw_f;   // reuse kk_f storage: kk dead once k_chain runs
  float* oF   = (float*)d_out;

  // 1. prep
  k_prep<<<16384, 256, 0, stream>>>(hs, x_r, x_w, x_k, x_v, x_a,
                                    xr_f, xw_f, xk_f, xv_f, xa_f);
  // 2. weight transposes
  SrcP sp; DstP dp;
  sp.p[0]=W_r; sp.p[1]=W_k; sp.p[2]=W_v; sp.p[3]=W_o;
  sp.p[4]=wla; sp.p[5]=wlb; sp.p[6]=ala; sp.p[7]=alb; sp.p[8]=gla; sp.p[9]=glb;
  dp.p[0]=Wr_t; dp.p[1]=Wk_t; dp.p[2]=Wv_t; dp.p[3]=Wo_t;
  dp.p[4]=wla_t; dp.p[5]=wlb_t; dp.p[6]=ala_t; dp.p[7]=alb_t; dp.p[8]=gla_t; dp.p[9]=glb_t;
  k_transpose<<<dim3(32,32,10), dim3(32,8), 0, stream>>>(sp, dp);

  // 3. big projections
  k_gemm_split<<<dim3(32,8), 256, 0, stream>>>(xr_f,1024, Wr_t,1024, r_f,1024, nullptr, 0, 1024);
  k_gemm_split<<<dim3(32,8), 256, 0, stream>>>(xk_f,1024, Wk_t,1024, k_f,1024, nullptr, 0, 1024);
  k_gemm_split<<<dim3(32,8), 256, 0, stream>>>(xv_f,1024, Wv_t,1024, v_f,1024, nullptr, 0, 1024);

  // 4. w-LoRA
  k_gemm_split<<<dim3(32,1), 256, 0, stream>>>(xw_f,1024, wla_t,1024, t1,128, nullptr, 0, 1024);
  k_act<<<1024, 256, 0, stream>>>(t1, t2, 6, 1);
  k_gemm_split<<<dim3(32,8), 256, 0, stream>>>(t2,64, wlb_t,64, ew_f,1024, wlbias, 1, 64);

  // 5. a-LoRA
  k_gemm_split<<<dim3(32,1), 256, 0, stream>>>(xa_f,1024, ala_t,1024, t1,128, nullptr, 0, 1024);
  k_act<<<1024, 256, 0, stream>>>(t1, t2, 6, 0);
  k_gemm_split<<<dim3(32,8), 256, 0, stream>>>(t2,64, alb_t,64, a_f,1024, albias, 2, 64);

  // 6. g-LoRA
  k_gemm_split<<<dim3(32,1), 256, 0, stream>>>(r_f,1024, gla_t,1024, t1,128, nullptr, 0, 1024);
  k_act<<<2048, 256, 0, stream>>>(t1, t2, 7, 2);
  k_gemm_split<<<dim3(32,8), 256, 0, stream>>>(t2,128, glb_t,128, g_f,1024, glbias, 3, 128);

  // 7. kk normalize + k update + b precompute
  k_scanprep<<<16384, 256, 0, stream>>>(k_f, a_f, k_k, k_a, kk_f);

  // 8. chunked scan
  k_scan_p1<<<1024, 512, 0, stream>>>(r_f, ew_f, k_f, v_f, kk_f, a_f, oF, z_f, Uc_f, PT_f);
  k_chain<<<32, 256, 0, stream>>>(Uc_f, PT_f, S0_f);
  k_correct<<<992, 256, 0, stream>>>(S0_f, z_f, oF);

  // 9. groupnorm + bonus + gate
  k_post<<<16384, 256, 0, stream>>>(oF, r_f, k_f, v_f, r_k, gnw, gnb, g_f, y_f);

  // 10. output projection (overwrites d_out)
  k_gemm_split<<<dim3(32,8), 256, 0, stream>>>(y_f,1024, Wo_t,1024, (float*)d_out,1024, nullptr, 0, 1024);
}

// Round 6
// 611.541 us; speedup vs baseline: 2.7216x; 1.0599x over previous
//
#include <hip/hip_runtime.h>
#include <hip/hip_bf16.h>
#include <stdint.h>
#include <stddef.h>

typedef __hip_bfloat16 bf16;
typedef __attribute__((ext_vector_type(8))) short short8;
typedef __attribute__((ext_vector_type(4))) float f32x4;

__device__ __forceinline__ float dsigm(float z){ return 1.f/(1.f+expf(-z)); }

// split fp32 -> hi (bit-truncated bf16) + lo (rounded bf16 residual); hi+lo ~ 16 mantissa bits
__device__ __forceinline__ void split1(float v, unsigned short& h, unsigned short& l) {
  unsigned int u = __builtin_bit_cast(unsigned int, v);
  h = (unsigned short)(u >> 16);
  float hf = __builtin_bit_cast(float, u & 0xFFFF0000u);
  bf16 lb = __float2bfloat16(v - hf);
  l = __builtin_bit_cast(unsigned short, lb);
}

__device__ __forceinline__ void split8(const float* f, short8& h, short8& l) {
#pragma unroll
  for (int e = 0; e < 8; ++e) {
    unsigned short hh, ll;
    split1(f[e], hh, ll);
    h[e] = (short)hh; l[e] = (short)ll;
  }
}

//==================== 1. time-shift lerp -> packed split-bf16 operands ====================
// Each output: ushort [4096][2048] = [hi cols 0..1023 | lo cols 1024..2047]
__device__ __forceinline__ void emit_pack(const float* __restrict__ marr, int c4,
    const float4& cur, const float4& dlt, unsigned short* __restrict__ out, int row)
{
  float4 m = *(const float4*)(marr + c4);
  float v0 = fmaf(dlt.x, m.x, cur.x);
  float v1 = fmaf(dlt.y, m.y, cur.y);
  float v2 = fmaf(dlt.z, m.z, cur.z);
  float v3 = fmaf(dlt.w, m.w, cur.w);
  unsigned short h0,h1,h2,h3,l0,l1,l2,l3;
  split1(v0,h0,l0); split1(v1,h1,l1); split1(v2,h2,l2); split1(v3,h3,l3);
  *(ushort4*)(out + (size_t)row*2048 + c4)        = make_ushort4(h0,h1,h2,h3);
  *(ushort4*)(out + (size_t)row*2048 + 1024 + c4) = make_ushort4(l0,l1,l2,l3);
}

__global__ void k_prep(const float* __restrict__ hs,
    const float* __restrict__ mr, const float* __restrict__ mw, const float* __restrict__ mk,
    const float* __restrict__ mv, const float* __restrict__ ma,
    unsigned short* __restrict__ oxr, unsigned short* __restrict__ oxw,
    unsigned short* __restrict__ oxk, unsigned short* __restrict__ oxv,
    unsigned short* __restrict__ oxa)
{
  int id = blockIdx.x * 256 + threadIdx.x;          // 1M threads, 4 elems each
  int row = id >> 8;
  int c4 = (id & 255) << 2;
  int t = row & 2047;
  const float* hp = hs + (size_t)row*1024 + c4;
  float4 cur = *(const float4*)hp;
  float4 prev = make_float4(0.f,0.f,0.f,0.f);
  if (t > 0) prev = *(const float4*)(hp - 1024);
  float4 dlt = make_float4(prev.x-cur.x, prev.y-cur.y, prev.z-cur.z, prev.w-cur.w);
  emit_pack(mr, c4, cur, dlt, oxr, row);
  emit_pack(mw, c4, cur, dlt, oxw, row);
  emit_pack(mk, c4, cur, dlt, oxk, row);
  emit_pack(mv, c4, cur, dlt, oxv, row);
  emit_pack(ma, c4, cur, dlt, oxa, row);
}

//==================== 2. weight transpose + split-bf16 pack ====================
// dst ushort [Cp][2R] = [hi | lo] of src[R][Cc]^T; pad rows zero.
struct SrcP { const float* p[10]; };
struct DstP { unsigned short* p[10]; };

__global__ void k_transpose(SrcP S, DstP Dd)
{
  static constexpr int TR[10]  = {1024,1024,1024,1024,1024,  64,1024,  64,1024, 128};
  static constexpr int TCC[10] = {1024,1024,1024,1024,  64,1024,  64,1024, 128,1024};
  static constexpr int TCP[10] = {1024,1024,1024,1024, 128,1024, 128,1024, 128,1024};
  int z = blockIdx.z;
  int R = TR[z], Cc = TCC[z], Cp = TCP[z];
  int n0 = blockIdx.x * 32, r0 = blockIdx.y * 32;
  if (n0 >= Cp || r0 >= R) return;
  const float* src = S.p[z];
  unsigned short* dst = Dd.p[z];
  int tx = threadIdx.x, ty = threadIdx.y;
  __shared__ float tile[32][33];
  if (n0 < Cc) {
#pragma unroll
    for (int i = 0; i < 4; ++i)
      tile[ty + 8*i][tx] = src[(size_t)(r0 + ty + 8*i)*Cc + n0 + tx];
    __syncthreads();
#pragma unroll
    for (int i = 0; i < 4; ++i) {
      float v = tile[tx][ty + 8*i];
      unsigned short h, lo;
      split1(v, h, lo);
      size_t nr = (size_t)(n0 + ty + 8*i);
      dst[nr*2*R + r0 + tx]     = h;
      dst[nr*2*R + R + r0 + tx] = lo;
    }
  } else {
#pragma unroll
    for (int i = 0; i < 4; ++i) {
      size_t nr = (size_t)(n0 + ty + 8*i);
      dst[nr*2*R + r0 + tx]     = 0;
      dst[nr*2*R + R + r0 + tx] = 0;
    }
  }
}

//==================== 3. batched augmented-K bf16 GEMM ====================
// C = A_fp32 @ B_fp32^T computed exactly as AhBh + AlBh + AhBl via K->3K:
//   A stored [M][2K] = [Ah|Al], Bt stored [N][2K] = [Bh|Bl]
//   aug kt: t0 (A hi, B hi), t1 (A lo, B hi), t2 (A hi, B lo)
// tile 128x128, BK=32, 4 waves. act: 0 none, 1 sigmoid, 2 tanh, 3 ew=e^-.5*sigmoid
struct GJob {
  const unsigned short* A;   // [4096][2K]
  const unsigned short* Bt;  // [N][2K]
  float* C;                  // optional fp32 out [4096][ldc]
  unsigned short* Cpk;       // optional packed out [4096][2*Npk]
  const float* bias;         // optional, by col (added before act)
  int K; int N; int Npk; int ldc; int act;
};
struct GJobs { GJob j[5]; };

__global__ __launch_bounds__(256) void k_gemm_bf(GJobs jobs)
{
  GJob jb = jobs.j[blockIdx.z];
  const int colBase = blockIdx.y * 128;
  if (colBase >= jb.N) return;
  const int rowBase = blockIdx.x * 128;
  __shared__ __align__(16) unsigned short As[128*32];
  __shared__ __align__(16) unsigned short Bs[128*32];
  const int tid = threadIdx.x;
  const int l = tid & 63, w = tid >> 6;
  const int wm = w >> 1, wn = w & 1;
  const int lrow = l & 15, kid = (l >> 4) * 8;
  const int lda = jb.K * 2;
  const int Knk = jb.K >> 5;

  f32x4 acc[4][4];
#pragma unroll
  for (int i = 0; i < 4; ++i)
#pragma unroll
    for (int j = 0; j < 4; ++j) { f32x4 z = {0.f,0.f,0.f,0.f}; acc[i][j] = z; }

  const int nk3 = 3 * Knk;
  for (int kka = 0; kka < nk3; ++kka) {
    const int aOff = ((kka >= 2*Knk) ? kka - 2*Knk : kka) * 32;
    const int bOff = ((kka >= Knk)   ? kka - Knk   : kka) * 32;
#pragma unroll
    for (int rr = 0; rr < 2; ++rr) {
      int idx = rr*256 + tid;
      int ar = idx >> 2, ac = (idx & 3) * 8;
      *(uint4*)(&As[ar*32 + ac]) = *(const uint4*)(jb.A  + (size_t)(rowBase + ar)*lda + aOff + ac);
      *(uint4*)(&Bs[ar*32 + ac]) = *(const uint4*)(jb.Bt + (size_t)(colBase + ar)*lda + bOff + ac);
    }
    __syncthreads();
    short8 af[4], bfr[4];
#pragma unroll
    for (int mt = 0; mt < 4; ++mt) af[mt]  = *(const short8*)&As[(wm*64 + mt*16 + lrow)*32 + kid];
#pragma unroll
    for (int nt = 0; nt < 4; ++nt) bfr[nt] = *(const short8*)&Bs[(wn*64 + nt*16 + lrow)*32 + kid];
#pragma unroll
    for (int mt = 0; mt < 4; ++mt)
#pragma unroll
      for (int nt = 0; nt < 4; ++nt)
        acc[mt][nt] = __builtin_amdgcn_mfma_f32_16x16x32_bf16(af[mt], bfr[nt], acc[mt][nt], 0, 0, 0);
    __syncthreads();
  }
#pragma unroll
  for (int mt = 0; mt < 4; ++mt) {
    int row = rowBase + wm*64 + mt*16 + (l >> 4)*4;
#pragma unroll
    for (int nt = 0; nt < 4; ++nt) {
      int col = colBase + wn*64 + nt*16 + (l & 15);
      float bv = (jb.bias != nullptr) ? jb.bias[col] : 0.f;
#pragma unroll
      for (int rg = 0; rg < 4; ++rg) {
        float v = acc[mt][nt][rg] + bv;
        if (jb.act == 1)      v = dsigm(v);
        else if (jb.act == 2) v = tanhf(v);
        else if (jb.act == 3) v = 0.60653066f * dsigm(v);
        if (jb.C) jb.C[(size_t)(row + rg)*jb.ldc + col] = v;
        if (jb.Cpk && col < jb.Npk) {
          unsigned short h, lo;
          split1(v, h, lo);
          unsigned short* pk = jb.Cpk + (size_t)(row + rg)*(2*jb.Npk);
          pk[col] = h;
          pk[jb.Npk + col] = lo;
        }
      }
    }
  }
}

//==================== 5. scan prep: kk normalize + k update + b=kk*a ====================
__global__ void k_scanprep(float* __restrict__ kA, float* __restrict__ aA,
                           const float* __restrict__ kkw, const float* __restrict__ kaw,
                           float* __restrict__ kkA)
{
  size_t gt = (size_t)blockIdx.x * 256u + threadIdx.x;
  int d = (int)(gt & 63);
  size_t flat = gt >> 6;
  int c = (int)((flat & 15) * 64 + d);
  float k0 = kA[gt], av = aA[gt];
  float kkv = k0 * kkw[c];
  float ss = kkv * kkv;
  ss += __shfl_xor(ss, 1);  ss += __shfl_xor(ss, 2);  ss += __shfl_xor(ss, 4);
  ss += __shfl_xor(ss, 8);  ss += __shfl_xor(ss, 16); ss += __shfl_xor(ss, 32);
  float inv = 1.f / fmaxf(sqrtf(ss), 1e-12f);
  float kkn = kkv * inv;
  kkA[gt] = kkn;               // a_scan = -kkn (negation applied in-kernel)
  aA[gt]  = kkn * av;          // b_scan = kkn * a_head
  kA[gt]  = k0 * fmaf(av - 1.f, kaw[c], 1.f);
}

//==================== 6a. chunked scan pass 1 (LDS-staged) ====================
#define SP1_EW 0
#define SP1_KK 512
#define SP1_BB 1024
#define SP1_KV 1536
#define SP1_RR 2048
#define SP1_VV 2560

__device__ __forceinline__ void step_lds(const float* __restrict__ sb, int s,
    float* u, float* p, float* __restrict__ o0A, float* __restrict__ zA,
    size_t base, int i, int q, int j0)
{
  float4 ew0 = *(const float4*)(sb + SP1_EW + s*64 + j0);
  float4 ew1 = *(const float4*)(sb + SP1_EW + s*64 + j0 + 4);
  float4 kk0 = *(const float4*)(sb + SP1_KK + s*64 + j0);
  float4 kk1 = *(const float4*)(sb + SP1_KK + s*64 + j0 + 4);
  float4 bb0 = *(const float4*)(sb + SP1_BB + s*64 + j0);
  float4 bb1 = *(const float4*)(sb + SP1_BB + s*64 + j0 + 4);
  float4 kv0 = *(const float4*)(sb + SP1_KV + s*64 + j0);
  float4 kv1 = *(const float4*)(sb + SP1_KV + s*64 + j0 + 4);
  float4 rr0 = *(const float4*)(sb + SP1_RR + s*64 + j0);
  float4 rr1 = *(const float4*)(sb + SP1_RR + s*64 + j0 + 4);
  float vi = sb[SP1_VV + s*64 + i];

  float uk = 0.f, pk = 0.f;
#define RED(SI, V, F) { uk += u[SI]*V.F; pk += p[SI]*V.F; }
  RED(0,kk0,x) RED(1,kk0,y) RED(2,kk0,z) RED(3,kk0,w)
  RED(4,kk1,x) RED(5,kk1,y) RED(6,kk1,z) RED(7,kk1,w)
#undef RED
  uk += __shfl_xor(uk, 1); uk += __shfl_xor(uk, 2); uk += __shfl_xor(uk, 4);
  pk += __shfl_xor(pk, 1); pk += __shfl_xor(pk, 2); pk += __shfl_xor(pk, 4);
  const float su = -uk, sp = -pk;
  float oo = 0.f, zz = 0.f;
#define UPD(SI, E, Kv, Bv, Rv, F) { \
    float uu = u[SI]*E.F + su*Bv.F + vi*Kv.F; u[SI] = uu; oo += uu*Rv.F; \
    float pp = p[SI]*E.F + sp*Bv.F;           p[SI] = pp; zz += pp*Rv.F; }
  UPD(0,ew0,kv0,bb0,rr0,x) UPD(1,ew0,kv0,bb0,rr0,y) UPD(2,ew0,kv0,bb0,rr0,z) UPD(3,ew0,kv0,bb0,rr0,w)
  UPD(4,ew1,kv1,bb1,rr1,x) UPD(5,ew1,kv1,bb1,rr1,y) UPD(6,ew1,kv1,bb1,rr1,z) UPD(7,ew1,kv1,bb1,rr1,w)
#undef UPD
  oo += __shfl_xor(oo, 1); oo += __shfl_xor(oo, 2); oo += __shfl_xor(oo, 4);
  zz += __shfl_xor(zz, 1); zz += __shfl_xor(zz, 2); zz += __shfl_xor(zz, 4);
  if (q == 0) { o0A[base + i] = oo; zA[base + i] = zz; }
}

__global__ __launch_bounds__(512) void k_scan_p1(
    const float* __restrict__ rA, const float* __restrict__ ewA,
    const float* __restrict__ kA, const float* __restrict__ vA,
    const float* __restrict__ kkA, const float* __restrict__ bbA,
    float* __restrict__ o0A, float* __restrict__ zA,
    float* __restrict__ UcA, float* __restrict__ PTcA)
{
  const int blk = blockIdx.x;
  const int bh = blk & 31, c = blk >> 5;
  const int b = bh >> 4, h = bh & 15;
  const int tid = threadIdx.x;
  const int i = tid >> 3, q = tid & 7, j0 = q * 8;
  const size_t base0 = (size_t)b*2048*1024 + (size_t)h*64 + (size_t)(c*64)*1024;

  __shared__ __align__(16) float smem[2*3072];

  const int a0 = tid >> 7, rm0 = tid & 127, s0 = rm0 >> 4, f40 = rm0 & 15;
  const float* pa0 = (a0 == 0) ? ewA : (a0 == 1) ? kkA : (a0 == 2) ? bbA : kA;
  const float* src0 = pa0 + base0 + (size_t)s0*1024 + f40*4;
  const int dst0 = a0*512 + s0*64 + f40*4;
  const int have2 = (tid < 256);
  const int a1 = ((tid + 512) >> 7);
  const int rm1 = (tid + 512) & 127, s1 = rm1 >> 4, f41 = rm1 & 15;
  const float* pa1 = (a1 == 4) ? rA : vA;
  const float* src1 = pa1 + base0 + (size_t)s1*1024 + f41*4;
  const int dst1 = a1*512 + s1*64 + f41*4;

  float u[8], p[8];
#pragma unroll
  for (int jj = 0; jj < 8; ++jj) { u[jj] = 0.f; p[jj] = (j0 + jj == i) ? 1.f : 0.f; }

  {
    float4 n0 = *(const float4*)(src0);
    float4 n1;
    if (have2) n1 = *(const float4*)(src1);
    *(float4*)&smem[dst0] = n0;
    if (have2) *(float4*)&smem[dst1] = n1;
  }
  __syncthreads();

  int curb = 0;
  for (int g = 0; g < 8; ++g) {
    float4 n0, n1;
    if (g < 7) {
      n0 = *(const float4*)(src0 + (size_t)(g+1)*8192);
      if (have2) n1 = *(const float4*)(src1 + (size_t)(g+1)*8192);
    }
    const float* sb = smem + curb*3072;
#pragma unroll
    for (int s = 0; s < 8; ++s)
      step_lds(sb, s, u, p, o0A, zA, base0 + (size_t)(g*8 + s)*1024, i, q, j0);
    if (g < 7) {
      int nb = curb ^ 1;
      *(float4*)&smem[nb*3072 + dst0] = n0;
      if (have2) *(float4*)&smem[nb*3072 + dst1] = n1;
    }
    __syncthreads();
    curb ^= 1;
  }

  const size_t cbase = ((size_t)(bh*32 + c)) * 4096;
  *(float4*)(UcA + cbase + (size_t)i*64 + j0)     = make_float4(u[0],u[1],u[2],u[3]);
  *(float4*)(UcA + cbase + (size_t)i*64 + j0 + 4) = make_float4(u[4],u[5],u[6],u[7]);
  float (*lds)[65] = (float(*)[65])smem;
#pragma unroll
  for (int jj = 0; jj < 8; ++jj) lds[i][j0 + jj] = p[jj];
  __syncthreads();
  float4 w0 = make_float4(lds[j0+0][i], lds[j0+1][i], lds[j0+2][i], lds[j0+3][i]);
  float4 w1 = make_float4(lds[j0+4][i], lds[j0+5][i], lds[j0+6][i], lds[j0+7][i]);
  *(float4*)(PTcA + cbase + (size_t)i*64 + j0)     = w0;
  *(float4*)(PTcA + cbase + (size_t)i*64 + j0 + 4) = w1;
}

//==================== 6b. chain: S_{c+1} = U_c + S_c @ P_c, store S0_c ====================
__device__ __forceinline__ void chain_body(int c, int bh, int w, int lr, int lq,
    float (&Slds)[64][65], f32x4 (&acc)[4],
    float (&u_c)[4][4], float4 (&p_c)[2][2],
    float (&u_n)[4][4], float4 (&p_n)[2][2],
    const float* __restrict__ UcA, const float* __restrict__ PTcA,
    float* __restrict__ S0A)
{
  const size_t s0base = ((size_t)bh*32 + c) * 4096;
#pragma unroll
  for (int mt = 0; mt < 4; ++mt)
#pragma unroll
    for (int rg = 0; rg < 4; ++rg) {
      Slds[mt*16 + lq*4 + rg][w*16 + lr] = acc[mt][rg];
      if (c > 0) S0A[s0base + (size_t)(mt*16 + lq*4 + rg)*64 + w*16 + lr] = acc[mt][rg];
    }
  __syncthreads();
  if (c + 1 < 32) {
    const size_t nbase = ((size_t)bh*32 + c + 1) * 4096;
#pragma unroll
    for (int mt = 0; mt < 4; ++mt)
#pragma unroll
      for (int rg = 0; rg < 4; ++rg)
        u_n[mt][rg] = UcA[nbase + (size_t)(mt*16 + lq*4 + rg)*64 + w*16 + lr];
#pragma unroll
    for (int kt = 0; kt < 2; ++kt)
#pragma unroll
      for (int hh = 0; hh < 2; ++hh)
        p_n[kt][hh] = *(const float4*)(PTcA + nbase + (size_t)(w*16 + lr)*64 + kt*32 + lq*8 + hh*4);
  }
  short8 pbh[2], pbl[2];
#pragma unroll
  for (int kt = 0; kt < 2; ++kt) {
    float f[8] = {p_c[kt][0].x, p_c[kt][0].y, p_c[kt][0].z, p_c[kt][0].w,
                  p_c[kt][1].x, p_c[kt][1].y, p_c[kt][1].z, p_c[kt][1].w};
    split8(f, pbh[kt], pbl[kt]);
  }
  f32x4 nacc[4];
#pragma unroll
  for (int mt = 0; mt < 4; ++mt) {
    f32x4 z = {u_c[mt][0], u_c[mt][1], u_c[mt][2], u_c[mt][3]};
    nacc[mt] = z;
  }
#pragma unroll
  for (int kt = 0; kt < 2; ++kt)
#pragma unroll
    for (int mt = 0; mt < 4; ++mt) {
      float f[8];
#pragma unroll
      for (int e = 0; e < 8; ++e) f[e] = Slds[mt*16 + lr][kt*32 + lq*8 + e];
      short8 sah, sal;
      split8(f, sah, sal);
      nacc[mt] = __builtin_amdgcn_mfma_f32_16x16x32_bf16(sah, pbh[kt], nacc[mt], 0, 0, 0);
      nacc[mt] = __builtin_amdgcn_mfma_f32_16x16x32_bf16(sal, pbh[kt], nacc[mt], 0, 0, 0);
      nacc[mt] = __builtin_amdgcn_mfma_f32_16x16x32_bf16(sah, pbl[kt], nacc[mt], 0, 0, 0);
    }
#pragma unroll
  for (int mt = 0; mt < 4; ++mt) acc[mt] = nacc[mt];
  __syncthreads();
}

__global__ __launch_bounds__(256) void k_chain(
    const float* __restrict__ UcA, const float* __restrict__ PTcA,
    float* __restrict__ S0A)
{
  const int bh = blockIdx.x;
  const int l = threadIdx.x & 63, w = threadIdx.x >> 6;
  const int lr = l & 15, lq = l >> 4;
  __shared__ float Slds[64][65];

  f32x4 acc[4];
#pragma unroll
  for (int mt = 0; mt < 4; ++mt) { f32x4 z = {0.f,0.f,0.f,0.f}; acc[mt] = z; }

  float u0[4][4], u1[4][4];
  float4 p0[2][2], p1[2][2];
  {
    const size_t cbase = (size_t)bh * 32 * 4096;
#pragma unroll
    for (int mt = 0; mt < 4; ++mt)
#pragma unroll
      for (int rg = 0; rg < 4; ++rg)
        u0[mt][rg] = UcA[cbase + (size_t)(mt*16 + lq*4 + rg)*64 + w*16 + lr];
#pragma unroll
    for (int kt = 0; kt < 2; ++kt)
#pragma unroll
      for (int hh = 0; hh < 2; ++hh)
        p0[kt][hh] = *(const float4*)(PTcA + cbase + (size_t)(w*16 + lr)*64 + kt*32 + lq*8 + hh*4);
  }
  for (int c = 0; c < 32; c += 2) {
    chain_body(c,     bh, w, lr, lq, Slds, acc, u0, p0, u1, p1, UcA, PTcA, S0A);
    chain_body(c + 1, bh, w, lr, lq, Slds, acc, u1, p1, u0, p0, UcA, PTcA, S0A);
  }
}

//==================== 6c. correction: o[c*64+tl] += Z_c @ S0_c^T ====================
__global__ __launch_bounds__(256) void k_correct(
    const float* __restrict__ S0A, const float* __restrict__ zA, float* __restrict__ oA)
{
  const int blk = blockIdx.x;
  const int bh = blk & 31;
  const int c  = (blk >> 5) + 1;
  const int b = bh >> 4, h = bh & 15;
  const int l = threadIdx.x & 63, w = threadIdx.x >> 6;
  const int lr = l & 15, lq = l >> 4;
  const size_t s0base = ((size_t)bh*32 + c) * 4096;

  short8 sbh[4][2], sbl[4][2];
#pragma unroll
  for (int nt = 0; nt < 4; ++nt)
#pragma unroll
    for (int kt = 0; kt < 2; ++kt) {
      float f[8];
#pragma unroll
      for (int e = 0; e < 8; ++e)
        f[e] = S0A[s0base + (size_t)(nt*16 + lr)*64 + kt*32 + lq*8 + e];
      split8(f, sbh[nt][kt], sbl[nt][kt]);
    }
  short8 zh[2], zl[2];
#pragma unroll
  for (int kt = 0; kt < 2; ++kt) {
    const float* zp = zA + ((size_t)(b*2048 + c*64 + w*16 + lr)*16 + h)*64 + kt*32 + lq*8;
    float f[8];
#pragma unroll
    for (int e = 0; e < 8; ++e) f[e] = zp[e];
    split8(f, zh[kt], zl[kt]);
  }
  f32x4 a2[4];
#pragma unroll
  for (int nt = 0; nt < 4; ++nt) { f32x4 z = {0.f,0.f,0.f,0.f}; a2[nt] = z; }
#pragma unroll
  for (int kt = 0; kt < 2; ++kt)
#pragma unroll
    for (int nt = 0; nt < 4; ++nt) {
      a2[nt] = __builtin_amdgcn_mfma_f32_16x16x32_bf16(zh[kt], sbh[nt][kt], a2[nt], 0, 0, 0);
      a2[nt] = __builtin_amdgcn_mfma_f32_16x16x32_bf16(zl[kt], sbh[nt][kt], a2[nt], 0, 0, 0);
      a2[nt] = __builtin_amdgcn_mfma_f32_16x16x32_bf16(zh[kt], sbl[nt][kt], a2[nt], 0, 0, 0);
    }
#pragma unroll
  for (int nt = 0; nt < 4; ++nt)
#pragma unroll
    for (int rg = 0; rg < 4; ++rg) {
      int tl = w*16 + lq*4 + rg, ii = nt*16 + lr;
      size_t ad = ((size_t)(b*2048 + c*64 + tl)*16 + h)*64 + ii;
      oA[ad] += a2[nt][rg];
    }
}

//==================== 7. GroupNorm + bonus + gate -> packed y ====================
__global__ void k_post(const float* __restrict__ oA, const float* __restrict__ rA,
    const float* __restrict__ kA, const float* __restrict__ vA,
    const float* __restrict__ rk, const float* __restrict__ gnw, const float* __restrict__ gnb,
    const float* __restrict__ gA, unsigned short* __restrict__ yPk)
{
  size_t gt = (size_t)blockIdx.x * 256u + threadIdx.x;
  int d = (int)(gt & 63);
  size_t flat = gt >> 6;
  int c = (int)((flat & 15) * 64 + d);
  float ov = oA[gt];
  float ss = ov;
  ss += __shfl_xor(ss, 1);  ss += __shfl_xor(ss, 2);  ss += __shfl_xor(ss, 4);
  ss += __shfl_xor(ss, 8);  ss += __shfl_xor(ss, 16); ss += __shfl_xor(ss, 32);
  float mean = ss * (1.f/64.f);
  float dm = ov - mean;
  float vv = dm * dm;
  vv += __shfl_xor(vv, 1);  vv += __shfl_xor(vv, 2);  vv += __shfl_xor(vv, 4);
  vv += __shfl_xor(vv, 8);  vv += __shfl_xor(vv, 16); vv += __shfl_xor(vv, 32);
  float var = vv * (1.f/64.f);
  float y = dm * rsqrtf(var + 1e-5f) * gnw[c] + gnb[c];
  float pr = rA[gt] * kA[gt] * rk[c];
  pr += __shfl_xor(pr, 1);  pr += __shfl_xor(pr, 2);  pr += __shfl_xor(pr, 4);
  pr += __shfl_xor(pr, 8);  pr += __shfl_xor(pr, 16); pr += __shfl_xor(pr, 32);
  y += pr * vA[gt];
  y *= gA[gt];
  int row = (int)(gt >> 10);
  int cc  = (int)(gt & 1023);
  unsigned short h, lo;
  split1(y, h, lo);
  yPk[(size_t)row*2048 + cc]        = h;
  yPk[(size_t)row*2048 + 1024 + cc] = lo;
}

//==================== host ====================
extern "C" void kernel_launch(void* const* d_in, const int* in_sizes, int n_in,
                              void* d_out, int out_size, void* d_ws, size_t ws_size,
                              hipStream_t stream)
{
  (void)in_sizes; (void)n_in; (void)out_size; (void)ws_size;
  const float* hs     = (const float*)d_in[0];
  const float* x_r    = (const float*)d_in[1];
  const float* x_w    = (const float*)d_in[2];
  const float* x_k    = (const float*)d_in[3];
  const float* x_v    = (const float*)d_in[4];
  const float* x_a    = (const float*)d_in[5];
  const float* k_k    = (const float*)d_in[7];
  const float* k_a    = (const float*)d_in[8];
  const float* r_k    = (const float*)d_in[9];
  const float* W_r    = (const float*)d_in[10];
  const float* W_k    = (const float*)d_in[11];
  const float* W_v    = (const float*)d_in[12];
  const float* W_o    = (const float*)d_in[13];
  const float* wla    = (const float*)d_in[14];
  const float* wlb    = (const float*)d_in[15];
  const float* wlbias = (const float*)d_in[16];
  const float* ala    = (const float*)d_in[17];
  const float* alb    = (const float*)d_in[18];
  const float* albias = (const float*)d_in[19];
  const float* gla    = (const float*)d_in[20];
  const float* glb    = (const float*)d_in[21];
  const float* glbias = (const float*)d_in[22];
  const float* gnw    = (const float*)d_in[23];
  const float* gnb    = (const float*)d_in[24];

  char* ws = (char*)d_ws;
  size_t cur = 0;
  auto take = [&](size_t bytes) { size_t o = cur; cur += (bytes + 255) & ~(size_t)255; return o; };

  typedef unsigned short us;
  // packed A operands [4096][2048] us
  us* xr_aug = (us*)(ws + take((size_t)4096*2048*2));
  us* xw_aug = (us*)(ws + take((size_t)4096*2048*2));
  us* xk_aug = (us*)(ws + take((size_t)4096*2048*2));
  us* xv_aug = (us*)(ws + take((size_t)4096*2048*2));
  us* xa_aug = (us*)(ws + take((size_t)4096*2048*2));
  // packed B operands
  us* Wr_p  = (us*)(ws + take((size_t)1024*2048*2));
  us* Wk_p  = (us*)(ws + take((size_t)1024*2048*2));
  us* Wv_p  = (us*)(ws + take((size_t)1024*2048*2));
  us* Wo_p  = (us*)(ws + take((size_t)1024*2048*2));
  us* wla_p = (us*)(ws + take((size_t)128*2048*2));
  us* wlb_p = (us*)(ws + take((size_t)1024*128*2));
  us* ala_p = (us*)(ws + take((size_t)128*2048*2));
  us* alb_p = (us*)(ws + take((size_t)1024*128*2));
  us* gla_p = (us*)(ws + take((size_t)128*2048*2));
  us* glb_p = (us*)(ws + take((size_t)1024*256*2));
  // chained packed A operands
  us* raug  = (us*)(ws + take((size_t)4096*2048*2));
  us* t2w   = (us*)(ws + take((size_t)4096*128*2));
  us* t2a   = (us*)(ws + take((size_t)4096*128*2));
  us* t2g   = (us*)(ws + take((size_t)4096*256*2));
  // fp32 scan operands
  float* r_f  = (float*)(ws + take((size_t)4096*1024*4));
  float* k_f  = (float*)(ws + take((size_t)4096*1024*4));
  float* v_f  = (float*)(ws + take((size_t)4096*1024*4));
  float* z_f  = (float*)(ws + take((size_t)4096*1024*4));
  float* Uc_f = (float*)(ws + take((size_t)4096*1024*4));
  float* PT_f = (float*)(ws + take((size_t)4096*1024*4));
  // aliases (lifetime-checked against launch order):
  float* kk_f = (float*)xr_aug;   // xr_aug dead after L2; kk used L5-L6; yaug reuses later
  float* ew_f = (float*)xw_aug;   // xw_aug dead after L2 (w-s1); ew written L3, read L6
  float* a_f  = (float*)xa_aug;   // xa_aug dead after L2 (a-s1); a written L3
  float* g_f  = (float*)xv_aug;   // xv_aug dead after L2 (v); g written L4, read L9
  float* S0_f = (float*)xk_aug;   // xk_aug dead after L2 (k); S0 written L7
  us*    yaug = xr_aug;           // kk dead after L6; y written L9, read L10
  float* oF   = (float*)d_out;

  // L1: prep (packs 5 operands)
  k_prep<<<4096, 256, 0, stream>>>(hs, x_r, x_w, x_k, x_v, x_a,
                                   xr_aug, xw_aug, xk_aug, xv_aug, xa_aug);
  // L1b: weight transpose+pack
  SrcP sp; DstP dp;
  sp.p[0]=W_r; sp.p[1]=W_k; sp.p[2]=W_v; sp.p[3]=W_o;
  sp.p[4]=wla; sp.p[5]=wlb; sp.p[6]=ala; sp.p[7]=alb; sp.p[8]=gla; sp.p[9]=glb;
  dp.p[0]=Wr_p; dp.p[1]=Wk_p; dp.p[2]=Wv_p; dp.p[3]=Wo_p;
  dp.p[4]=wla_p; dp.p[5]=wlb_p; dp.p[6]=ala_p; dp.p[7]=alb_p; dp.p[8]=gla_p; dp.p[9]=glb_p;
  k_transpose<<<dim3(32,32,10), dim3(32,8), 0, stream>>>(sp, dp);

  GJobs J{};
  auto job = [](const us* A, const us* Bt, float* C, us* Cpk, const float* bias,
                int K, int N, int Npk, int ldc, int act) {
    GJob j; j.A=A; j.Bt=Bt; j.C=C; j.Cpk=Cpk; j.bias=bias;
    j.K=K; j.N=N; j.Npk=Npk; j.ldc=ldc; j.act=act; return j;
  };

  // L2: r(+pack), k, v, w-s1(tanh,pack), a-s1(pack)
  J.j[0] = job(xr_aug, Wr_p,  r_f, raug, nullptr, 1024, 1024, 1024, 1024, 0);
  J.j[1] = job(xk_aug, Wk_p,  k_f, nullptr, nullptr, 1024, 1024, 0, 1024, 0);
  J.j[2] = job(xv_aug, Wv_p,  v_f, nullptr, nullptr, 1024, 1024, 0, 1024, 0);
  J.j[3] = job(xw_aug, wla_p, nullptr, t2w, nullptr, 1024, 128, 64, 0, 2);
  J.j[4] = job(xa_aug, ala_p, nullptr, t2a, nullptr, 1024, 128, 64, 0, 0);
  k_gemm_bf<<<dim3(32,8,5), 256, 0, stream>>>(J);

  // L3: w-s2 (ew), a-s2 (sigmoid), g-s1 (sigmoid, pack)
  J = GJobs{};
  J.j[0] = job(t2w,  wlb_p, ew_f, nullptr, wlbias, 64, 1024, 0, 1024, 3);
  J.j[1] = job(t2a,  alb_p, a_f,  nullptr, albias, 64, 1024, 0, 1024, 1);
  J.j[2] = job(raug, gla_p, nullptr, t2g, nullptr, 1024, 128, 128, 0, 1);
  k_gemm_bf<<<dim3(32,8,3), 256, 0, stream>>>(J);

  // L4: g-s2 (+bias)
  J = GJobs{};
  J.j[0] = job(t2g, glb_p, g_f, nullptr, glbias, 128, 1024, 0, 1024, 0);
  k_gemm_bf<<<dim3(32,8,1), 256, 0, stream>>>(J);

  // L5: kk normalize + k update + b precompute
  k_scanprep<<<16384, 256, 0, stream>>>(k_f, a_f, k_k, k_a, kk_f);

  // L6-L8: chunked scan
  k_scan_p1<<<1024, 512, 0, stream>>>(r_f, ew_f, k_f, v_f, kk_f, a_f, oF, z_f, Uc_f, PT_f);
  k_chain<<<32, 256, 0, stream>>>(Uc_f, PT_f, S0_f);
  k_correct<<<992, 256, 0, stream>>>(S0_f, z_f, oF);

  // L9: groupnorm + bonus + gate -> packed y
  k_post<<<16384, 256, 0, stream>>>(oF, r_f, k_f, v_f, r_k, gnw, gnb, g_f, yaug);

  // L10: output projection (overwrites d_out)
  J = GJobs{};
  J.j[0] = job(yaug, Wo_p, (float*)d_out, nullptr, nullptr, 1024, 1024, 0, 1024, 0);
  k_gemm_bf<<<dim3(32,8,1), 256, 0, stream>>>(J);
}

// Round 7
// 497.818 us; speedup vs baseline: 3.3433x; 1.2284x over previous
//
#include <hip/hip_runtime.h>
#include <hip/hip_bf16.h>
#include <stdint.h>
#include <stddef.h>

typedef __hip_bfloat16 bf16;
typedef __attribute__((ext_vector_type(8))) short short8;
typedef __attribute__((ext_vector_type(4))) float f32x4;

__device__ __forceinline__ float dsigm(float z){ return 1.f/(1.f+expf(-z)); }

// split fp32 -> hi (bit-truncated bf16) + lo (rounded bf16 residual); hi+lo ~ 16 mantissa bits
__device__ __forceinline__ void split1(float v, unsigned short& h, unsigned short& l) {
  unsigned int u = __builtin_bit_cast(unsigned int, v);
  h = (unsigned short)(u >> 16);
  float hf = __builtin_bit_cast(float, u & 0xFFFF0000u);
  bf16 lb = __float2bfloat16(v - hf);
  l = __builtin_bit_cast(unsigned short, lb);
}

__device__ __forceinline__ void split8(const float* f, short8& h, short8& l) {
#pragma unroll
  for (int e = 0; e < 8; ++e) {
    unsigned short hh, ll;
    split1(f[e], hh, ll);
    h[e] = (short)hh; l[e] = (short)ll;
  }
}

// async global->LDS, 16B per lane (dest = wave-uniform base + lane*16)
__device__ __forceinline__ void gl16(const unsigned short* g, unsigned short* l) {
  __builtin_amdgcn_global_load_lds((const __attribute__((address_space(1))) void*)g,
                                   (__attribute__((address_space(3))) void*)l, 16, 0, 0);
}

//==================== 1. time-shift lerp -> packed split-bf16 operands ====================
__device__ __forceinline__ void emit_pack(const float* __restrict__ marr, int c4,
    const float4& cur, const float4& dlt, unsigned short* __restrict__ out, int row)
{
  float4 m = *(const float4*)(marr + c4);
  float v0 = fmaf(dlt.x, m.x, cur.x);
  float v1 = fmaf(dlt.y, m.y, cur.y);
  float v2 = fmaf(dlt.z, m.z, cur.z);
  float v3 = fmaf(dlt.w, m.w, cur.w);
  unsigned short h0,h1,h2,h3,l0,l1,l2,l3;
  split1(v0,h0,l0); split1(v1,h1,l1); split1(v2,h2,l2); split1(v3,h3,l3);
  *(ushort4*)(out + (size_t)row*2048 + c4)        = make_ushort4(h0,h1,h2,h3);
  *(ushort4*)(out + (size_t)row*2048 + 1024 + c4) = make_ushort4(l0,l1,l2,l3);
}

__global__ void k_prep(const float* __restrict__ hs,
    const float* __restrict__ mr, const float* __restrict__ mw, const float* __restrict__ mk,
    const float* __restrict__ mv, const float* __restrict__ ma,
    unsigned short* __restrict__ oxr, unsigned short* __restrict__ oxw,
    unsigned short* __restrict__ oxk, unsigned short* __restrict__ oxv,
    unsigned short* __restrict__ oxa)
{
  int id = blockIdx.x * 256 + threadIdx.x;
  int row = id >> 8;
  int c4 = (id & 255) << 2;
  int t = row & 2047;
  const float* hp = hs + (size_t)row*1024 + c4;
  float4 cur = *(const float4*)hp;
  float4 prev = make_float4(0.f,0.f,0.f,0.f);
  if (t > 0) prev = *(const float4*)(hp - 1024);
  float4 dlt = make_float4(prev.x-cur.x, prev.y-cur.y, prev.z-cur.z, prev.w-cur.w);
  emit_pack(mr, c4, cur, dlt, oxr, row);
  emit_pack(mw, c4, cur, dlt, oxw, row);
  emit_pack(mk, c4, cur, dlt, oxk, row);
  emit_pack(mv, c4, cur, dlt, oxv, row);
  emit_pack(ma, c4, cur, dlt, oxa, row);
}

//==================== 2. weight transpose + split-bf16 pack ====================
struct SrcP { const float* p[10]; };
struct DstP { unsigned short* p[10]; };

__global__ void k_transpose(SrcP S, DstP Dd)
{
  static constexpr int TR[10]  = {1024,1024,1024,1024,1024,  64,1024,  64,1024, 128};
  static constexpr int TCC[10] = {1024,1024,1024,1024,  64,1024,  64,1024, 128,1024};
  static constexpr int TCP[10] = {1024,1024,1024,1024, 128,1024, 128,1024, 128,1024};
  int z = blockIdx.z;
  int R = TR[z], Cc = TCC[z], Cp = TCP[z];
  int n0 = blockIdx.x * 32, r0 = blockIdx.y * 32;
  if (n0 >= Cp || r0 >= R) return;
  const float* src = S.p[z];
  unsigned short* dst = Dd.p[z];
  int tx = threadIdx.x, ty = threadIdx.y;
  __shared__ float tile[32][33];
  if (n0 < Cc) {
#pragma unroll
    for (int i = 0; i < 4; ++i)
      tile[ty + 8*i][tx] = src[(size_t)(r0 + ty + 8*i)*Cc + n0 + tx];
    __syncthreads();
#pragma unroll
    for (int i = 0; i < 4; ++i) {
      float v = tile[tx][ty + 8*i];
      unsigned short h, lo;
      split1(v, h, lo);
      size_t nr = (size_t)(n0 + ty + 8*i);
      dst[nr*2*R + r0 + tx]     = h;
      dst[nr*2*R + R + r0 + tx] = lo;
    }
  } else {
#pragma unroll
    for (int i = 0; i < 4; ++i) {
      size_t nr = (size_t)(n0 + ty + 8*i);
      dst[nr*2*R + r0 + tx]     = 0;
      dst[nr*2*R + R + r0 + tx] = 0;
    }
  }
}

//==================== 3. batched split-bf16 GEMM (fp32-exact, 3-term) ====================
// C = A_fp32 @ B_fp32^T as AhBh + AlBh + AhBl.
//   A stored [M][2K] = [Ah|Al], Bt stored [N][2K] = [Bh|Bl]
// Per K-block (32): stage Ah,Al,Bh,Bl tiles via global_load_lds (width 16),
// then 3 MFMA passes from LDS. 2 barriers / 48 MFMA per K-block.
struct GJob {
  const unsigned short* A;   // [4096][2K]
  const unsigned short* Bt;  // [N][2K]
  float* C;                  // optional fp32 out [4096][ldc]
  unsigned short* Cpk;       // optional packed out [4096][2*Npk]
  const float* bias;         // optional, by col (added before act)
  int K; int N; int Npk; int ldc; int act;
};
struct GJobs { GJob j[5]; };

__global__ __launch_bounds__(256) void k_gemm_bf(GJobs jobs)
{
  GJob jb = jobs.j[blockIdx.z];
  const int colBase = blockIdx.y * 128;
  if (colBase >= jb.N) return;
  const int rowBase = blockIdx.x * 128;
  __shared__ __align__(16) unsigned short AsH[128*32];
  __shared__ __align__(16) unsigned short AsL[128*32];
  __shared__ __align__(16) unsigned short BsH[128*32];
  __shared__ __align__(16) unsigned short BsL[128*32];
  const int tid = threadIdx.x;
  const int l = tid & 63, w = tid >> 6;
  const int wm = w >> 1, wn = w & 1;
  const int lrow = l & 15, kid = (l >> 4) * 8;
  const int K = jb.K;
  const int lda = K * 2;
  const int nk = K >> 5;

  // staging geometry: call i (i=0,1): linear slot s=(i*4+w)*64+l; row=s>>2, oct=s&3
  const int s0 = (0*4 + w)*64 + l, s1 = (1*4 + w)*64 + l;
  const int ar0 = s0 >> 2, ac0 = (s0 & 3) * 8;
  const int ar1 = s1 >> 2, ac1 = (s1 & 3) * 8;
  const int ld0 = (0*4 + w)*512;       // ushort offset of this wave's 1KB chunk
  const int ld1 = (1*4 + w)*512;
  const unsigned short* Arow0 = jb.A  + (size_t)(rowBase + ar0)*lda + ac0;
  const unsigned short* Arow1 = jb.A  + (size_t)(rowBase + ar1)*lda + ac1;
  const unsigned short* Brow0 = jb.Bt + (size_t)(colBase + ar0)*lda + ac0;
  const unsigned short* Brow1 = jb.Bt + (size_t)(colBase + ar1)*lda + ac1;

  f32x4 acc[4][4];
#pragma unroll
  for (int i = 0; i < 4; ++i)
#pragma unroll
    for (int j = 0; j < 4; ++j) { f32x4 z = {0.f,0.f,0.f,0.f}; acc[i][j] = z; }

  for (int kt = 0; kt < nk; ++kt) {
    const int kh = kt*32;        // hi cols
    const int klo = K + kt*32;   // lo cols
    gl16(Arow0 + kh,  &AsH[ld0]);  gl16(Arow1 + kh,  &AsH[ld1]);
    gl16(Arow0 + klo, &AsL[ld0]);  gl16(Arow1 + klo, &AsL[ld1]);
    gl16(Brow0 + kh,  &BsH[ld0]);  gl16(Brow1 + kh,  &BsH[ld1]);
    gl16(Brow0 + klo, &BsL[ld0]);  gl16(Brow1 + klo, &BsL[ld1]);
    __syncthreads();

    short8 ah[4], al[4], bh[4], bl[4];
#pragma unroll
    for (int mt = 0; mt < 4; ++mt) {
      int ro = (wm*64 + mt*16 + lrow)*32 + kid;
      ah[mt] = *(const short8*)&AsH[ro];
      al[mt] = *(const short8*)&AsL[ro];
    }
#pragma unroll
    for (int nt = 0; nt < 4; ++nt) {
      int ro = (wn*64 + nt*16 + lrow)*32 + kid;
      bh[nt] = *(const short8*)&BsH[ro];
      bl[nt] = *(const short8*)&BsL[ro];
    }
#pragma unroll
    for (int mt = 0; mt < 4; ++mt)
#pragma unroll
      for (int nt = 0; nt < 4; ++nt) {
        acc[mt][nt] = __builtin_amdgcn_mfma_f32_16x16x32_bf16(ah[mt], bh[nt], acc[mt][nt], 0, 0, 0);
        acc[mt][nt] = __builtin_amdgcn_mfma_f32_16x16x32_bf16(al[mt], bh[nt], acc[mt][nt], 0, 0, 0);
        acc[mt][nt] = __builtin_amdgcn_mfma_f32_16x16x32_bf16(ah[mt], bl[nt], acc[mt][nt], 0, 0, 0);
      }
    __syncthreads();
  }
#pragma unroll
  for (int mt = 0; mt < 4; ++mt) {
    int row = rowBase + wm*64 + mt*16 + (l >> 4)*4;
#pragma unroll
    for (int nt = 0; nt < 4; ++nt) {
      int col = colBase + wn*64 + nt*16 + (l & 15);
      float bv = (jb.bias != nullptr) ? jb.bias[col] : 0.f;
#pragma unroll
      for (int rg = 0; rg < 4; ++rg) {
        float v = acc[mt][nt][rg] + bv;
        if (jb.act == 1)      v = dsigm(v);
        else if (jb.act == 2) v = tanhf(v);
        else if (jb.act == 3) v = 0.60653066f * dsigm(v);
        if (jb.C) jb.C[(size_t)(row + rg)*jb.ldc + col] = v;
        if (jb.Cpk && col < jb.Npk) {
          unsigned short h, lo;
          split1(v, h, lo);
          unsigned short* pk = jb.Cpk + (size_t)(row + rg)*(2*jb.Npk);
          pk[col] = h;
          pk[jb.Npk + col] = lo;
        }
      }
    }
  }
}

//==================== 5. scan prep: kk normalize + k update + b=kk*a ====================
__global__ void k_scanprep(float* __restrict__ kA, float* __restrict__ aA,
                           const float* __restrict__ kkw, const float* __restrict__ kaw,
                           float* __restrict__ kkA)
{
  size_t gt = (size_t)blockIdx.x * 256u + threadIdx.x;
  int d = (int)(gt & 63);
  size_t flat = gt >> 6;
  int c = (int)((flat & 15) * 64 + d);
  float k0 = kA[gt], av = aA[gt];
  float kkv = k0 * kkw[c];
  float ss = kkv * kkv;
  ss += __shfl_xor(ss, 1);  ss += __shfl_xor(ss, 2);  ss += __shfl_xor(ss, 4);
  ss += __shfl_xor(ss, 8);  ss += __shfl_xor(ss, 16); ss += __shfl_xor(ss, 32);
  float inv = 1.f / fmaxf(sqrtf(ss), 1e-12f);
  float kkn = kkv * inv;
  kkA[gt] = kkn;
  aA[gt]  = kkn * av;
  kA[gt]  = k0 * fmaf(av - 1.f, kaw[c], 1.f);
}

//==================== 6a. chunked scan pass 1 (LDS-staged) ====================
#define SP1_EW 0
#define SP1_KK 512
#define SP1_BB 1024
#define SP1_KV 1536
#define SP1_RR 2048
#define SP1_VV 2560

__device__ __forceinline__ void step_lds(const float* __restrict__ sb, int s,
    float* u, float* p, float* __restrict__ o0A, float* __restrict__ zA,
    size_t base, int i, int q, int j0)
{
  float4 ew0 = *(const float4*)(sb + SP1_EW + s*64 + j0);
  float4 ew1 = *(const float4*)(sb + SP1_EW + s*64 + j0 + 4);
  float4 kk0 = *(const float4*)(sb + SP1_KK + s*64 + j0);
  float4 kk1 = *(const float4*)(sb + SP1_KK + s*64 + j0 + 4);
  float4 bb0 = *(const float4*)(sb + SP1_BB + s*64 + j0);
  float4 bb1 = *(const float4*)(sb + SP1_BB + s*64 + j0 + 4);
  float4 kv0 = *(const float4*)(sb + SP1_KV + s*64 + j0);
  float4 kv1 = *(const float4*)(sb + SP1_KV + s*64 + j0 + 4);
  float4 rr0 = *(const float4*)(sb + SP1_RR + s*64 + j0);
  float4 rr1 = *(const float4*)(sb + SP1_RR + s*64 + j0 + 4);
  float vi = sb[SP1_VV + s*64 + i];

  float uk = 0.f, pk = 0.f;
#define RED(SI, V, F) { uk += u[SI]*V.F; pk += p[SI]*V.F; }
  RED(0,kk0,x) RED(1,kk0,y) RED(2,kk0,z) RED(3,kk0,w)
  RED(4,kk1,x) RED(5,kk1,y) RED(6,kk1,z) RED(7,kk1,w)
#undef RED
  uk += __shfl_xor(uk, 1); uk += __shfl_xor(uk, 2); uk += __shfl_xor(uk, 4);
  pk += __shfl_xor(pk, 1); pk += __shfl_xor(pk, 2); pk += __shfl_xor(pk, 4);
  const float su = -uk, sp = -pk;
  float oo = 0.f, zz = 0.f;
#define UPD(SI, E, Kv, Bv, Rv, F) { \
    float uu = u[SI]*E.F + su*Bv.F + vi*Kv.F; u[SI] = uu; oo += uu*Rv.F; \
    float pp = p[SI]*E.F + sp*Bv.F;           p[SI] = pp; zz += pp*Rv.F; }
  UPD(0,ew0,kv0,bb0,rr0,x) UPD(1,ew0,kv0,bb0,rr0,y) UPD(2,ew0,kv0,bb0,rr0,z) UPD(3,ew0,kv0,bb0,rr0,w)
  UPD(4,ew1,kv1,bb1,rr1,x) UPD(5,ew1,kv1,bb1,rr1,y) UPD(6,ew1,kv1,bb1,rr1,z) UPD(7,ew1,kv1,bb1,rr1,w)
#undef UPD
  oo += __shfl_xor(oo, 1); oo += __shfl_xor(oo, 2); oo += __shfl_xor(oo, 4);
  zz += __shfl_xor(zz, 1); zz += __shfl_xor(zz, 2); zz += __shfl_xor(zz, 4);
  if (q == 0) { o0A[base + i] = oo; zA[base + i] = zz; }
}

__global__ __launch_bounds__(512) void k_scan_p1(
    const float* __restrict__ rA, const float* __restrict__ ewA,
    const float* __restrict__ kA, const float* __restrict__ vA,
    const float* __restrict__ kkA, const float* __restrict__ bbA,
    float* __restrict__ o0A, float* __restrict__ zA,
    float* __restrict__ UcA, float* __restrict__ PTcA)
{
  const int blk = blockIdx.x;
  const int bh = blk & 31, c = blk >> 5;
  const int b = bh >> 4, h = bh & 15;
  const int tid = threadIdx.x;
  const int i = tid >> 3, q = tid & 7, j0 = q * 8;
  const size_t base0 = (size_t)b*2048*1024 + (size_t)h*64 + (size_t)(c*64)*1024;

  __shared__ __align__(16) float smem[2*3072];

  const int a0 = tid >> 7, rm0 = tid & 127, s0 = rm0 >> 4, f40 = rm0 & 15;
  const float* pa0 = (a0 == 0) ? ewA : (a0 == 1) ? kkA : (a0 == 2) ? bbA : kA;
  const float* src0 = pa0 + base0 + (size_t)s0*1024 + f40*4;
  const int dst0 = a0*512 + s0*64 + f40*4;
  const int have2 = (tid < 256);
  const int a1 = ((tid + 512) >> 7);
  const int rm1 = (tid + 512) & 127, s1 = rm1 >> 4, f41 = rm1 & 15;
  const float* pa1 = (a1 == 4) ? rA : vA;
  const float* src1 = pa1 + base0 + (size_t)s1*1024 + f41*4;
  const int dst1 = a1*512 + s1*64 + f41*4;

  float u[8], p[8];
#pragma unroll
  for (int jj = 0; jj < 8; ++jj) { u[jj] = 0.f; p[jj] = (j0 + jj == i) ? 1.f : 0.f; }

  {
    float4 n0 = *(const float4*)(src0);
    float4 n1;
    if (have2) n1 = *(const float4*)(src1);
    *(float4*)&smem[dst0] = n0;
    if (have2) *(float4*)&smem[dst1] = n1;
  }
  __syncthreads();

  int curb = 0;
  for (int g = 0; g < 8; ++g) {
    float4 n0, n1;
    if (g < 7) {
      n0 = *(const float4*)(src0 + (size_t)(g+1)*8192);
      if (have2) n1 = *(const float4*)(src1 + (size_t)(g+1)*8192);
    }
    const float* sb = smem + curb*3072;
#pragma unroll
    for (int s = 0; s < 8; ++s)
      step_lds(sb, s, u, p, o0A, zA, base0 + (size_t)(g*8 + s)*1024, i, q, j0);
    if (g < 7) {
      int nb = curb ^ 1;
      *(float4*)&smem[nb*3072 + dst0] = n0;
      if (have2) *(float4*)&smem[nb*3072 + dst1] = n1;
    }
    __syncthreads();
    curb ^= 1;
  }

  const size_t cbase = ((size_t)(bh*32 + c)) * 4096;
  *(float4*)(UcA + cbase + (size_t)i*64 + j0)     = make_float4(u[0],u[1],u[2],u[3]);
  *(float4*)(UcA + cbase + (size_t)i*64 + j0 + 4) = make_float4(u[4],u[5],u[6],u[7]);
  float (*lds)[65] = (float(*)[65])smem;
#pragma unroll
  for (int jj = 0; jj < 8; ++jj) lds[i][j0 + jj] = p[jj];
  __syncthreads();
  float4 w0 = make_float4(lds[j0+0][i], lds[j0+1][i], lds[j0+2][i], lds[j0+3][i]);
  float4 w1 = make_float4(lds[j0+4][i], lds[j0+5][i], lds[j0+6][i], lds[j0+7][i]);
  *(float4*)(PTcA + cbase + (size_t)i*64 + j0)     = w0;
  *(float4*)(PTcA + cbase + (size_t)i*64 + j0 + 4) = w1;
}

//==================== 6b. chain: S_{c+1} = U_c + S_c @ P_c, store S0_c ====================
__device__ __forceinline__ void chain_body(int c, int bh, int w, int lr, int lq,
    float (&Slds)[64][65], f32x4 (&acc)[4],
    float (&u_c)[4][4], float4 (&p_c)[2][2],
    float (&u_n)[4][4], float4 (&p_n)[2][2],
    const float* __restrict__ UcA, const float* __restrict__ PTcA,
    float* __restrict__ S0A)
{
  const size_t s0base = ((size_t)bh*32 + c) * 4096;
#pragma unroll
  for (int mt = 0; mt < 4; ++mt)
#pragma unroll
    for (int rg = 0; rg < 4; ++rg) {
      Slds[mt*16 + lq*4 + rg][w*16 + lr] = acc[mt][rg];
      if (c > 0) S0A[s0base + (size_t)(mt*16 + lq*4 + rg)*64 + w*16 + lr] = acc[mt][rg];
    }
  __syncthreads();
  if (c + 1 < 32) {
    const size_t nbase = ((size_t)bh*32 + c + 1) * 4096;
#pragma unroll
    for (int mt = 0; mt < 4; ++mt)
#pragma unroll
      for (int rg = 0; rg < 4; ++rg)
        u_n[mt][rg] = UcA[nbase + (size_t)(mt*16 + lq*4 + rg)*64 + w*16 + lr];
#pragma unroll
    for (int kt = 0; kt < 2; ++kt)
#pragma unroll
      for (int hh = 0; hh < 2; ++hh)
        p_n[kt][hh] = *(const float4*)(PTcA + nbase + (size_t)(w*16 + lr)*64 + kt*32 + lq*8 + hh*4);
  }
  short8 pbh[2], pbl[2];
#pragma unroll
  for (int kt = 0; kt < 2; ++kt) {
    float f[8] = {p_c[kt][0].x, p_c[kt][0].y, p_c[kt][0].z, p_c[kt][0].w,
                  p_c[kt][1].x, p_c[kt][1].y, p_c[kt][1].z, p_c[kt][1].w};
    split8(f, pbh[kt], pbl[kt]);
  }
  f32x4 nacc[4];
#pragma unroll
  for (int mt = 0; mt < 4; ++mt) {
    f32x4 z = {u_c[mt][0], u_c[mt][1], u_c[mt][2], u_c[mt][3]};
    nacc[mt] = z;
  }
#pragma unroll
  for (int kt = 0; kt < 2; ++kt)
#pragma unroll
    for (int mt = 0; mt < 4; ++mt) {
      float f[8];
#pragma unroll
      for (int e = 0; e < 8; ++e) f[e] = Slds[mt*16 + lr][kt*32 + lq*8 + e];
      short8 sah, sal;
      split8(f, sah, sal);
      nacc[mt] = __builtin_amdgcn_mfma_f32_16x16x32_bf16(sah, pbh[kt], nacc[mt], 0, 0, 0);
      nacc[mt] = __builtin_amdgcn_mfma_f32_16x16x32_bf16(sal, pbh[kt], nacc[mt], 0, 0, 0);
      nacc[mt] = __builtin_amdgcn_mfma_f32_16x16x32_bf16(sah, pbl[kt], nacc[mt], 0, 0, 0);
    }
#pragma unroll
  for (int mt = 0; mt < 4; ++mt) acc[mt] = nacc[mt];
  __syncthreads();
}

__global__ __launch_bounds__(256) void k_chain(
    const float* __restrict__ UcA, const float* __restrict__ PTcA,
    float* __restrict__ S0A)
{
  const int bh = blockIdx.x;
  const int l = threadIdx.x & 63, w = threadIdx.x >> 6;
  const int lr = l & 15, lq = l >> 4;
  __shared__ float Slds[64][65];

  f32x4 acc[4];
#pragma unroll
  for (int mt = 0; mt < 4; ++mt) { f32x4 z = {0.f,0.f,0.f,0.f}; acc[mt] = z; }

  float u0[4][4], u1[4][4];
  float4 p0[2][2], p1[2][2];
  {
    const size_t cbase = (size_t)bh * 32 * 4096;
#pragma unroll
    for (int mt = 0; mt < 4; ++mt)
#pragma unroll
      for (int rg = 0; rg < 4; ++rg)
        u0[mt][rg] = UcA[cbase + (size_t)(mt*16 + lq*4 + rg)*64 + w*16 + lr];
#pragma unroll
    for (int kt = 0; kt < 2; ++kt)
#pragma unroll
      for (int hh = 0; hh < 2; ++hh)
        p0[kt][hh] = *(const float4*)(PTcA + cbase + (size_t)(w*16 + lr)*64 + kt*32 + lq*8 + hh*4);
  }
  for (int c = 0; c < 32; c += 2) {
    chain_body(c,     bh, w, lr, lq, Slds, acc, u0, p0, u1, p1, UcA, PTcA, S0A);
    chain_body(c + 1, bh, w, lr, lq, Slds, acc, u1, p1, u0, p0, UcA, PTcA, S0A);
  }
}

//==================== 6c. correction: o[c*64+tl] += Z_c @ S0_c^T ====================
__global__ __launch_bounds__(256) void k_correct(
    const float* __restrict__ S0A, const float* __restrict__ zA, float* __restrict__ oA)
{
  const int blk = blockIdx.x;
  const int bh = blk & 31;
  const int c  = (blk >> 5) + 1;
  const int b = bh >> 4, h = bh & 15;
  const int l = threadIdx.x & 63, w = threadIdx.x >> 6;
  const int lr = l & 15, lq = l >> 4;
  const size_t s0base = ((size_t)bh*32 + c) * 4096;

  short8 sbh[4][2], sbl[4][2];
#pragma unroll
  for (int nt = 0; nt < 4; ++nt)
#pragma unroll
    for (int kt = 0; kt < 2; ++kt) {
      float f[8];
#pragma unroll
      for (int e = 0; e < 8; ++e)
        f[e] = S0A[s0base + (size_t)(nt*16 + lr)*64 + kt*32 + lq*8 + e];
      split8(f, sbh[nt][kt], sbl[nt][kt]);
    }
  short8 zh[2], zl[2];
#pragma unroll
  for (int kt = 0; kt < 2; ++kt) {
    const float* zp = zA + ((size_t)(b*2048 + c*64 + w*16 + lr)*16 + h)*64 + kt*32 + lq*8;
    float f[8];
#pragma unroll
    for (int e = 0; e < 8; ++e) f[e] = zp[e];
    split8(f, zh[kt], zl[kt]);
  }
  f32x4 a2[4];
#pragma unroll
  for (int nt = 0; nt < 4; ++nt) { f32x4 z = {0.f,0.f,0.f,0.f}; a2[nt] = z; }
#pragma unroll
  for (int kt = 0; kt < 2; ++kt)
#pragma unroll
    for (int nt = 0; nt < 4; ++nt) {
      a2[nt] = __builtin_amdgcn_mfma_f32_16x16x32_bf16(zh[kt], sbh[nt][kt], a2[nt], 0, 0, 0);
      a2[nt] = __builtin_amdgcn_mfma_f32_16x16x32_bf16(zl[kt], sbh[nt][kt], a2[nt], 0, 0, 0);
      a2[nt] = __builtin_amdgcn_mfma_f32_16x16x32_bf16(zh[kt], sbl[nt][kt], a2[nt], 0, 0, 0);
    }
#pragma unroll
  for (int nt = 0; nt < 4; ++nt)
#pragma unroll
    for (int rg = 0; rg < 4; ++rg) {
      int tl = w*16 + lq*4 + rg, ii = nt*16 + lr;
      size_t ad = ((size_t)(b*2048 + c*64 + tl)*16 + h)*64 + ii;
      oA[ad] += a2[nt][rg];
    }
}

//==================== 7. GroupNorm + bonus + gate -> packed y ====================
__global__ void k_post(const float* __restrict__ oA, const float* __restrict__ rA,
    const float* __restrict__ kA, const float* __restrict__ vA,
    const float* __restrict__ rk, const float* __restrict__ gnw, const float* __restrict__ gnb,
    const float* __restrict__ gA, unsigned short* __restrict__ yPk)
{
  size_t gt = (size_t)blockIdx.x * 256u + threadIdx.x;
  int d = (int)(gt & 63);
  size_t flat = gt >> 6;
  int c = (int)((flat & 15) * 64 + d);
  float ov = oA[gt];
  float ss = ov;
  ss += __shfl_xor(ss, 1);  ss += __shfl_xor(ss, 2);  ss += __shfl_xor(ss, 4);
  ss += __shfl_xor(ss, 8);  ss += __shfl_xor(ss, 16); ss += __shfl_xor(ss, 32);
  float mean = ss * (1.f/64.f);
  float dm = ov - mean;
  float vv = dm * dm;
  vv += __shfl_xor(vv, 1);  vv += __shfl_xor(vv, 2);  vv += __shfl_xor(vv, 4);
  vv += __shfl_xor(vv, 8);  vv += __shfl_xor(vv, 16); vv += __shfl_xor(vv, 32);
  float var = vv * (1.f/64.f);
  float y = dm * rsqrtf(var + 1e-5f) * gnw[c] + gnb[c];
  float pr = rA[gt] * kA[gt] * rk[c];
  pr += __shfl_xor(pr, 1);  pr += __shfl_xor(pr, 2);  pr += __shfl_xor(pr, 4);
  pr += __shfl_xor(pr, 8);  pr += __shfl_xor(pr, 16); pr += __shfl_xor(pr, 32);
  y += pr * vA[gt];
  y *= gA[gt];
  int row = (int)(gt >> 10);
  int cc  = (int)(gt & 1023);
  unsigned short h, lo;
  split1(y, h, lo);
  yPk[(size_t)row*2048 + cc]        = h;
  yPk[(size_t)row*2048 + 1024 + cc] = lo;
}

//==================== host ====================
extern "C" void kernel_launch(void* const* d_in, const int* in_sizes, int n_in,
                              void* d_out, int out_size, void* d_ws, size_t ws_size,
                              hipStream_t stream)
{
  (void)in_sizes; (void)n_in; (void)out_size; (void)ws_size;
  const float* hs     = (const float*)d_in[0];
  const float* x_r    = (const float*)d_in[1];
  const float* x_w    = (const float*)d_in[2];
  const float* x_k    = (const float*)d_in[3];
  const float* x_v    = (const float*)d_in[4];
  const float* x_a    = (const float*)d_in[5];
  const float* k_k    = (const float*)d_in[7];
  const float* k_a    = (const float*)d_in[8];
  const float* r_k    = (const float*)d_in[9];
  const float* W_r    = (const float*)d_in[10];
  const float* W_k    = (const float*)d_in[11];
  const float* W_v    = (const float*)d_in[12];
  const float* W_o    = (const float*)d_in[13];
  const float* wla    = (const float*)d_in[14];
  const float* wlb    = (const float*)d_in[15];
  const float* wlbias = (const float*)d_in[16];
  const float* ala    = (const float*)d_in[17];
  const float* alb    = (const float*)d_in[18];
  const float* albias = (const float*)d_in[19];
  const float* gla    = (const float*)d_in[20];
  const float* glb    = (const float*)d_in[21];
  const float* glbias = (const float*)d_in[22];
  const float* gnw    = (const float*)d_in[23];
  const float* gnb    = (const float*)d_in[24];

  char* ws = (char*)d_ws;
  size_t cur = 0;
  auto take = [&](size_t bytes) { size_t o = cur; cur += (bytes + 255) & ~(size_t)255; return o; };

  typedef unsigned short us;
  us* xr_aug = (us*)(ws + take((size_t)4096*2048*2));
  us* xw_aug = (us*)(ws + take((size_t)4096*2048*2));
  us* xk_aug = (us*)(ws + take((size_t)4096*2048*2));
  us* xv_aug = (us*)(ws + take((size_t)4096*2048*2));
  us* xa_aug = (us*)(ws + take((size_t)4096*2048*2));
  us* Wr_p  = (us*)(ws + take((size_t)1024*2048*2));
  us* Wk_p  = (us*)(ws + take((size_t)1024*2048*2));
  us* Wv_p  = (us*)(ws + take((size_t)1024*2048*2));
  us* Wo_p  = (us*)(ws + take((size_t)1024*2048*2));
  us* wla_p = (us*)(ws + take((size_t)128*2048*2));
  us* wlb_p = (us*)(ws + take((size_t)1024*128*2));
  us* ala_p = (us*)(ws + take((size_t)128*2048*2));
  us* alb_p = (us*)(ws + take((size_t)1024*128*2));
  us* gla_p = (us*)(ws + take((size_t)128*2048*2));
  us* glb_p = (us*)(ws + take((size_t)1024*256*2));
  us* raug  = (us*)(ws + take((size_t)4096*2048*2));
  us* t2w   = (us*)(ws + take((size_t)4096*128*2));
  us* t2a   = (us*)(ws + take((size_t)4096*128*2));
  us* t2g   = (us*)(ws + take((size_t)4096*256*2));
  float* r_f  = (float*)(ws + take((size_t)4096*1024*4));
  float* k_f  = (float*)(ws + take((size_t)4096*1024*4));
  float* v_f  = (float*)(ws + take((size_t)4096*1024*4));
  float* z_f  = (float*)(ws + take((size_t)4096*1024*4));
  float* Uc_f = (float*)(ws + take((size_t)4096*1024*4));
  float* PT_f = (float*)(ws + take((size_t)4096*1024*4));
  // aliases (lifetime-checked against launch order):
  float* kk_f = (float*)xr_aug;   // xr_aug dead after L2; kk used L5-L6
  float* ew_f = (float*)xw_aug;   // xw_aug dead after L2 (w-s1); ew written L3, read L6
  float* a_f  = (float*)xa_aug;   // xa_aug dead after L2 (a-s1); a written L3
  float* g_f  = (float*)xv_aug;   // xv_aug dead after L2 (v); g written L4, read L9
  float* S0_f = (float*)xk_aug;   // xk_aug dead after L2 (k); S0 written L7
  us*    yaug = xr_aug;           // kk dead after L6; y written L9, read L10
  float* oF   = (float*)d_out;

  // L1: prep (packs 5 operands)
  k_prep<<<4096, 256, 0, stream>>>(hs, x_r, x_w, x_k, x_v, x_a,
                                   xr_aug, xw_aug, xk_aug, xv_aug, xa_aug);
  // L1b: weight transpose+pack
  SrcP sp; DstP dp;
  sp.p[0]=W_r; sp.p[1]=W_k; sp.p[2]=W_v; sp.p[3]=W_o;
  sp.p[4]=wla; sp.p[5]=wlb; sp.p[6]=ala; sp.p[7]=alb; sp.p[8]=gla; sp.p[9]=glb;
  dp.p[0]=Wr_p; dp.p[1]=Wk_p; dp.p[2]=Wv_p; dp.p[3]=Wo_p;
  dp.p[4]=wla_p; dp.p[5]=wlb_p; dp.p[6]=ala_p; dp.p[7]=alb_p; dp.p[8]=gla_p; dp.p[9]=glb_p;
  k_transpose<<<dim3(32,32,10), dim3(32,8), 0, stream>>>(sp, dp);

  GJobs J{};
  auto job = [](const us* A, const us* Bt, float* C, us* Cpk, const float* bias,
                int K, int N, int Npk, int ldc, int act) {
    GJob j; j.A=A; j.Bt=Bt; j.C=C; j.Cpk=Cpk; j.bias=bias;
    j.K=K; j.N=N; j.Npk=Npk; j.ldc=ldc; j.act=act; return j;
  };

  // L2: r(+pack), k, v, w-s1(tanh,pack), a-s1(pack)
  J.j[0] = job(xr_aug, Wr_p,  r_f, raug, nullptr, 1024, 1024, 1024, 1024, 0);
  J.j[1] = job(xk_aug, Wk_p,  k_f, nullptr, nullptr, 1024, 1024, 0, 1024, 0);
  J.j[2] = job(xv_aug, Wv_p,  v_f, nullptr, nullptr, 1024, 1024, 0, 1024, 0);
  J.j[3] = job(xw_aug, wla_p, nullptr, t2w, nullptr, 1024, 128, 64, 0, 2);
  J.j[4] = job(xa_aug, ala_p, nullptr, t2a, nullptr, 1024, 128, 64, 0, 0);
  k_gemm_bf<<<dim3(32,8,5), 256, 0, stream>>>(J);

  // L3: w-s2 (ew), a-s2 (sigmoid), g-s1 (sigmoid, pack)
  J = GJobs{};
  J.j[0] = job(t2w,  wlb_p, ew_f, nullptr, wlbias, 64, 1024, 0, 1024, 3);
  J.j[1] = job(t2a,  alb_p, a_f,  nullptr, albias, 64, 1024, 0, 1024, 1);
  J.j[2] = job(raug, gla_p, nullptr, t2g, nullptr, 1024, 128, 128, 0, 1);
  k_gemm_bf<<<dim3(32,8,3), 256, 0, stream>>>(J);

  // L4: g-s2 (+bias)
  J = GJobs{};
  J.j[0] = job(t2g, glb_p, g_f, nullptr, glbias, 128, 1024, 0, 1024, 0);
  k_gemm_bf<<<dim3(32,8,1), 256, 0, stream>>>(J);

  // L5: kk normalize + k update + b precompute
  k_scanprep<<<16384, 256, 0, stream>>>(k_f, a_f, k_k, k_a, kk_f);

  // L6-L8: chunked scan
  k_scan_p1<<<1024, 512, 0, stream>>>(r_f, ew_f, k_f, v_f, kk_f, a_f, oF, z_f, Uc_f, PT_f);
  k_chain<<<32, 256, 0, stream>>>(Uc_f, PT_f, S0_f);
  k_correct<<<992, 256, 0, stream>>>(S0_f, z_f, oF);

  // L9: groupnorm + bonus + gate -> packed y
  k_post<<<16384, 256, 0, stream>>>(oF, r_f, k_f, v_f, r_k, gnw, gnb, g_f, yaug);

  // L10: output projection (overwrites d_out)
  J = GJobs{};
  J.j[0] = job(yaug, Wo_p, (float*)d_out, nullptr, nullptr, 1024, 1024, 0, 1024, 0);
  k_gemm_bf<<<dim3(32,8,1), 256, 0, stream>>>(J);
}